// Round 3
// baseline (163.936 us; speedup 1.0000x reference)
//
#include <hip/hip_runtime.h>

#define DEV __device__ __forceinline__

typedef __bf16 bf16x8 __attribute__((ext_vector_type(8)));
typedef __bf16 bf16x4 __attribute__((ext_vector_type(4)));
typedef float floatx4 __attribute__((ext_vector_type(4)));

// ---------------- K0: fused prep: cvt weights + pool ctx + transpose x ----
__global__ __launch_bounds__(256)
void prep_kernel(const float* __restrict__ Wq, const float* __restrict__ Wdy,
                 const float* __restrict__ ctx, const float* __restrict__ x,
                 __bf16* __restrict__ wqb, __bf16* __restrict__ wdyb,
                 float* __restrict__ kctx, __bf16* __restrict__ xt) {
  __shared__ float tile[64][65];
  int bid = blockIdx.x, t = threadIdx.x;
  if (bid < 256) {                       // weight cvt
    int i = bid * 256 + t;
    wqb[i]  = (__bf16)Wq[i];
    wdyb[i] = (__bf16)Wdy[i];
  } else if (bid < 512) {                // pool ctx 56x56 -> 7x7, one wave per (b,c)
    int bc = (bid - 256) * 4 + (t >> 6);
    const float* src = ctx + (size_t)bc * (56 * 56);
    int w = t & 63;
#pragma unroll
    for (int pi = 0; pi < 7; ++pi) {
      float s = 0.f;
      if (w < 56) {
#pragma unroll
        for (int di = 0; di < 8; ++di) s += src[(pi * 8 + di) * 56 + w];
      }
      s += __shfl_down(s, 4);
      s += __shfl_down(s, 2);
      s += __shfl_down(s, 1);
      if (w < 56 && (w & 7) == 0)
        kctx[(size_t)bc * 49 + pi * 7 + (w >> 3)] = s * (1.f / 64.f);
    }
  } else {                               // XT[b][n][c] = bf16(x[b][c][n])
    int idx = bid - 512;
    int b = idx >> 8, c0 = ((idx >> 6) & 3) * 64, n0 = (idx & 63) * 64;
    int lane = t & 63, rg = t >> 6;
    const float* src = x + ((size_t)b * 256 + c0) * 4096 + n0;
    for (int i = rg; i < 64; i += 4) tile[i][lane] = src[(size_t)i * 4096 + lane];
    __syncthreads();
    __bf16* dst = xt + ((size_t)b * 4096 + n0) * 256 + c0;
    for (int i = rg; i < 64; i += 4) dst[(size_t)i * 256 + lane] = (__bf16)tile[lane][i];
  }
}

// ---------------- K2: kf = LN(Wk @ kctx) per (b,l) ----------------
__global__ __launch_bounds__(256)
void kf_ln_kernel(const float* __restrict__ kctx, const float* __restrict__ Wk,
                  const float* __restrict__ gk, const float* __restrict__ bk,
                  float* __restrict__ kf) {
  int b = blockIdx.x / 49, l = blockIdx.x % 49;
  __shared__ float xs[256];
  __shared__ float r1[4], r2[4];
  int o = threadIdx.x;
  xs[o] = kctx[((size_t)b * 256 + o) * 49 + l];
  __syncthreads();
  const float* wrow = Wk + (size_t)o * 256;
  float acc = 0.f;
#pragma unroll 8
  for (int c = 0; c < 256; c += 4) {
    float4 wv = *(const float4*)(wrow + c);
    acc += wv.x * xs[c] + wv.y * xs[c + 1] + wv.z * xs[c + 2] + wv.w * xs[c + 3];
  }
  float s1 = acc, s2 = acc * acc;
#pragma unroll
  for (int off = 32; off > 0; off >>= 1) {
    s1 += __shfl_down(s1, off);
    s2 += __shfl_down(s2, off);
  }
  int wv_ = o >> 6, ln = o & 63;
  if (ln == 0) { r1[wv_] = s1; r2[wv_] = s2; }
  __syncthreads();
  float mu  = (r1[0] + r1[1] + r1[2] + r1[3]) * (1.f / 256.f);
  float var = (r2[0] + r2[1] + r2[2] + r2[3]) * (1.f / 256.f) - mu * mu;
  float rstd = rsqrtf(var + 1e-6f);
  kf[((size_t)b * 256 + o) * 49 + l] = (acc - mu) * rstd * gk[o] + bk[o];
}

// ------- K2b: kfpT[bg][m(80)][d(64)] = bf16( sum_l kf[b][g*64+d][l] * Wproj[m][l] ) -------
__global__ __launch_bounds__(256)
void kfp_kernel(const float* __restrict__ kf, const float* __restrict__ Wproj,
                __bf16* __restrict__ kfpT) {
  int bg = blockIdx.x; int b = bg >> 2, g = bg & 3;
  int m0 = blockIdx.y * 16;
  __shared__ float kfs[64][50];
  __shared__ float wps[16][50];
  int t = threadIdx.x;
  for (int i = t; i < 64 * 49; i += 256) {
    int d = i / 49, l = i % 49;
    kfs[d][l] = kf[((size_t)b * 256 + g * 64 + d) * 49 + l];
  }
  for (int i = t; i < 16 * 49; i += 256) {
    int m = i / 49, l = i % 49;
    wps[m][l] = (m0 + m < 74) ? Wproj[(m0 + m) * 49 + l] : 0.f;
  }
  __syncthreads();
  for (int i = t; i < 64 * 16; i += 256) {
    int d = i >> 4, m = i & 15;
    float s = 0.f;
    if (m0 + m < 74) {
#pragma unroll 7
      for (int l = 0; l < 49; ++l) s += kfs[d][l] * wps[m][l];
    }
    kfpT[(size_t)bg * 5120 + (m0 + m) * 64 + d] = (__bf16)s;
  }
}

// ---------------- softmax helpers (unchanged, proven) ----------------
DEV int rep_idx(int p, int kc, int t1, int sub) {
  return p < kc ? p : (p < t1 ? kc : p - sub);
}

template <int KK>
DEV void softmax_write(const float* wms, const float* rpb_s, __bf16* __restrict__ attnL,
                       int bg, int n_glob, int row) {
  constexpr int CNT = KK * KK;
  constexpr int RS  = 2 * KK - 1;
  constexpr int KC  = KK / 2;
  constexpr int T1  = KC + (64 - KK + 1);
  constexpr int SUB = 64 - KK;
  constexpr int MLO = (KK == 5) ? 0 : 25;
  constexpr int PW  = (KK == 5) ? 32 : 56;    // padded width (multiple of 8)
  int h = n_glob >> 6, w = n_glob & 63;
  int rh = rep_idx(63 - h, KC, T1, SUB);
  int rw = rep_idx(63 - w, KC, T1, SUB);
  float vals[CNT];
  float mx = -1e30f;
#pragma unroll
  for (int m = 0; m < CNT; ++m) {
    int ki = m / KK, kj = m % KK;
    float v = wms[row * 81 + MLO + m] + rpb_s[(rh + ki) * RS + rw + kj];
    vals[m] = v; mx = fmaxf(mx, v);
  }
  float ssum = 0.f;
#pragma unroll
  for (int m = 0; m < CNT; ++m) { float e = __expf(vals[m] - mx); vals[m] = e; ssum += e; }
  float inv = 1.f / ssum;
  __bf16 hv[PW];
#pragma unroll
  for (int m = 0; m < PW; ++m) hv[m] = (__bf16)(m < CNT ? vals[m] * inv : 0.f);
  __bf16* ap = attnL + ((size_t)bg * 4096 + n_glob) * 56;
#pragma unroll
  for (int i = 0; i < PW / 8; ++i) *(bf16x8*)(ap + i * 8) = *(bf16x8*)&hv[i * 8];
}

// ---------------- K3: fused q-GEMM + LN + QK-proj MFMA + softmax (NT=32) ----------------
// Block = (32-n tile, b). 4 waves; wave wv owns o-quadrant / head-group g = wv.
// LDS ~48 KB -> 2 blocks/CU (grid 512 = 2/CU): cross-block TLP hides phase-1 load latency.
__global__ __launch_bounds__(256, 2)
void qattn_kernel(const __bf16* __restrict__ Wb, const __bf16* __restrict__ XT,
                  const __bf16* __restrict__ kfpT,
                  const float* __restrict__ gq, const float* __restrict__ bq,
                  const float* __restrict__ rpb1, const float* __restrict__ rpb2,
                  __bf16* __restrict__ attnL) {
  __shared__ float wms[128 * 81];        // 41.5 KB, overlaid: As/Bs -> Aat -> wms
  __shared__ float rpb_s[500];           // rpb1 [0..161], rpb2 [162..499]
  __shared__ float gqs[256], bqs[256];
  __shared__ float red_s[128], red_q[128];
  __shared__ float st_mu[32], st_rs[32];
  __bf16* As  = (__bf16*)wms;            // [256 o][32 k] = 16384 B
  __bf16* Bs  = (__bf16*)wms + 8192;     // [32 n][32 k]  = 2048 B
  __bf16* Aat = (__bf16*)wms;            // [4 g][32 n][72 d] = 18432 B

  int b  = blockIdx.z;
  int n0 = blockIdx.x * 32;
  int t  = threadIdx.x;
  int lane = t & 63, wv = t >> 6;        // wv == head-group g
  int col = lane & 15, quad = lane >> 4;

  gqs[t] = gq[t] * 0.125f;               // SCALE folded
  bqs[t] = bq[t] * 0.125f;
  for (int i = t; i < 162; i += 256) rpb_s[i] = rpb1[i];
  for (int i = t; i < 338; i += 256) rpb_s[162 + i] = rpb2[i];

  // ---- phase 1: q = Wq @ x, M=256(o) x N=32(n) x K=256, reg-prefetched ----
  floatx4 acc[4][2];
#pragma unroll
  for (int i = 0; i < 4; ++i)
#pragma unroll
    for (int j = 0; j < 2; ++j) acc[i][j] = {0.f, 0.f, 0.f, 0.f};

  const __bf16* wp = Wb + (size_t)t * 256;       // one W row per thread
  int rowB = t >> 3, kB = (t & 7) * 4;           // 32 n rows x 32 k
  const __bf16* xp = XT + ((size_t)b * 4096 + n0 + rowB) * 256 + kB;
  bf16x8 ra0 = *(const bf16x8*)(wp + 0);
  bf16x8 ra1 = *(const bf16x8*)(wp + 8);
  bf16x8 ra2 = *(const bf16x8*)(wp + 16);
  bf16x8 ra3 = *(const bf16x8*)(wp + 24);
  bf16x4 rb  = *(const bf16x4*)xp;

  for (int c0 = 0; c0 < 256; c0 += 32) {
    *(bf16x8*)&As[t * 32 + 0]  = ra0;
    *(bf16x8*)&As[t * 32 + 8]  = ra1;
    *(bf16x8*)&As[t * 32 + 16] = ra2;
    *(bf16x8*)&As[t * 32 + 24] = ra3;
    *(bf16x4*)&Bs[rowB * 32 + kB] = rb;
    __syncthreads();
    if (c0 + 32 < 256) {                 // prefetch next K-tile; hides under MFMA
      ra0 = *(const bf16x8*)(wp + c0 + 32);
      ra1 = *(const bf16x8*)(wp + c0 + 40);
      ra2 = *(const bf16x8*)(wp + c0 + 48);
      ra3 = *(const bf16x8*)(wp + c0 + 56);
      rb  = *(const bf16x4*)(xp + c0 + 32);
    }
    bf16x8 fa[4], fb[2];
#pragma unroll
    for (int i = 0; i < 4; ++i)
      fa[i] = *(const bf16x8*)&As[(wv * 64 + i * 16 + col) * 32 + quad * 8];
#pragma unroll
    for (int j = 0; j < 2; ++j)
      fb[j] = *(const bf16x8*)&Bs[(j * 16 + col) * 32 + quad * 8];
#pragma unroll
    for (int i = 0; i < 4; ++i)
#pragma unroll
      for (int j = 0; j < 2; ++j)
        acc[i][j] = __builtin_amdgcn_mfma_f32_16x16x32_bf16(fa[i], fb[j], acc[i][j], 0, 0, 0);
    __syncthreads();
  }

  // ---- phase 2: LN stats over o (exact f32) ----
  // lane holds o = wv*64 + i*16 + quad*4 + r ; n_loc = j*16 + col
#pragma unroll
  for (int j = 0; j < 2; ++j) {
    float s = 0.f, q = 0.f;
#pragma unroll
    for (int i = 0; i < 4; ++i)
#pragma unroll
      for (int r = 0; r < 4; ++r) { float v = acc[i][j][r]; s += v; q += v * v; }
    s += __shfl_xor(s, 16); s += __shfl_xor(s, 32);   // reduce over quad
    q += __shfl_xor(q, 16); q += __shfl_xor(q, 32);
    if (quad == 0) {
      red_s[wv * 32 + j * 16 + col] = s;
      red_q[wv * 32 + j * 16 + col] = q;
    }
  }
  __syncthreads();
  if (t < 32) {
    float s = red_s[t] + red_s[32 + t] + red_s[64 + t] + red_s[96 + t];
    float q = red_q[t] + red_q[32 + t] + red_q[64 + t] + red_q[96 + t];
    float mu  = s * (1.f / 256.f);
    float var = q * (1.f / 256.f) - mu * mu;
    st_mu[t] = mu;
    st_rs[t] = rsqrtf(var + 1e-6f);
  }
  __syncthreads();

  // ---- phase 3: q-hat -> Aat (A-fragment layout), then attn MFMA ----
#pragma unroll
  for (int j = 0; j < 2; ++j) {
    float mu = st_mu[j * 16 + col], rs = st_rs[j * 16 + col];
#pragma unroll
    for (int i = 0; i < 4; ++i) {
      __bf16 pk[4];
#pragma unroll
      for (int r = 0; r < 4; ++r) {
        int o = wv * 64 + i * 16 + quad * 4 + r;
        pk[r] = (__bf16)((acc[i][j][r] - mu) * rs * gqs[o] + bqs[o]);
      }
      *(bf16x4*)&Aat[(wv * 32 + j * 16 + col) * 72 + i * 16 + quad * 4] = *(bf16x4*)pk;
    }
  }
  __syncthreads();

  bf16x8 fa2[2][2], fb2[2][5];
  const __bf16* kp = kfpT + (size_t)(b * 4 + wv) * 5120;   // L2-hot, 10 KB/wave
#pragma unroll
  for (int ks = 0; ks < 2; ++ks) {
#pragma unroll
    for (int a = 0; a < 2; ++a)
      fa2[ks][a] = *(const bf16x8*)&Aat[(wv * 32 + a * 16 + col) * 72 + ks * 32 + quad * 8];
#pragma unroll
    for (int nt = 0; nt < 5; ++nt)
      fb2[ks][nt] = *(const bf16x8*)&kp[(nt * 16 + col) * 64 + ks * 32 + quad * 8];
  }
  floatx4 acc2[2][5];
#pragma unroll
  for (int a = 0; a < 2; ++a)
#pragma unroll
    for (int nt = 0; nt < 5; ++nt) acc2[a][nt] = {0.f, 0.f, 0.f, 0.f};
#pragma unroll
  for (int ks = 0; ks < 2; ++ks)
#pragma unroll
    for (int a = 0; a < 2; ++a)
#pragma unroll
      for (int nt = 0; nt < 5; ++nt)
        acc2[a][nt] = __builtin_amdgcn_mfma_f32_16x16x32_bf16(fa2[ks][a], fb2[ks][nt], acc2[a][nt], 0, 0, 0);
  __syncthreads();   // all Aat reads done before wms overwrite

  // wgt rows: wave wv owns rows [wv*32, wv*32+32)
#pragma unroll
  for (int a = 0; a < 2; ++a)
#pragma unroll
    for (int nt = 0; nt < 5; ++nt)
#pragma unroll
      for (int r = 0; r < 4; ++r)
        wms[(wv * 32 + a * 16 + quad * 4 + r) * 81 + nt * 16 + col] = acc2[a][nt][r];
  __syncthreads();

  // ---- phase 4: softmax, one row per thread (128 rows = 32 n x 4 g) ----
  if (t < 128) {
    int g2 = t >> 5;
    int n_glob = n0 + (t & 31);
    int bg = b * 4 + g2;
    if (g2 < 2) softmax_write<5>(wms, rpb_s + g2 * 81,              attnL, bg, n_glob, t);
    else        softmax_write<7>(wms, rpb_s + 162 + (g2 - 2) * 169, attnL, bg, n_glob, t);
  }
}

// ---------------- K-out: bf16 MFMA 1x1 conv, reg-prefetched K-loop ----------------
// MODE 1: B = midT planar [b*4+g][n][64]; out fp32 [o][n] + BN affine.
template <int MODE>
__global__ __launch_bounds__(256, 2)
void conv_mfma_kernel(const __bf16* __restrict__ Wb, const __bf16* __restrict__ Xin,
                      void* __restrict__ Yout, float* __restrict__ stats,
                      const float* __restrict__ bn_g, const float* __restrict__ bn_b) {
  int b  = blockIdx.z;
  int n0 = blockIdx.x * 128;
  int o0 = blockIdx.y * 128;
  __shared__ __bf16 As[128 * 32];   // [m][k]
  __shared__ __bf16 Bs[128 * 32];   // [n][k]
  int t = threadIdx.x;
  int lane = t & 63, wv = t >> 6;
  int mq = (wv & 1) * 64, nq = (wv >> 1) * 64;
  int col = lane & 15, quad = lane >> 4;
  floatx4 acc[4][4];
#pragma unroll
  for (int i = 0; i < 4; ++i)
#pragma unroll
    for (int j = 0; j < 4; ++j) acc[i][j] = {0.f, 0.f, 0.f, 0.f};
  int sm = t >> 1, sk = (t & 1) << 4;
  const __bf16* wp = Wb + (size_t)(o0 + sm) * 256 + sk;
  auto xaddr = [&](int c0) -> const __bf16* {
    if (MODE == 0) {
      return Xin + ((size_t)b * 4096 + n0 + sm) * 256 + c0 + sk;
    } else {
      int c = c0 + sk, g = c >> 6, c64 = c & 63;   // 16-elem load stays in-plane
      return Xin + (((size_t)(b * 4 + g)) * 4096 + n0 + sm) * 64 + c64;
    }
  };
  bf16x8 wa0 = *(const bf16x8*)wp;
  bf16x8 wa1 = *(const bf16x8*)(wp + 8);
  const __bf16* x0 = xaddr(0);
  bf16x8 xb0 = *(const bf16x8*)x0;
  bf16x8 xb1 = *(const bf16x8*)(x0 + 8);
  for (int c0 = 0; c0 < 256; c0 += 32) {
    *(bf16x8*)&As[sm * 32 + sk]     = wa0;
    *(bf16x8*)&As[sm * 32 + sk + 8] = wa1;
    *(bf16x8*)&Bs[sm * 32 + sk]     = xb0;
    *(bf16x8*)&Bs[sm * 32 + sk + 8] = xb1;
    __syncthreads();
    if (c0 + 32 < 256) {               // prefetch next K-tile; hides under MFMA
      wa0 = *(const bf16x8*)(wp + c0 + 32);
      wa1 = *(const bf16x8*)(wp + c0 + 40);
      const __bf16* xn = xaddr(c0 + 32);
      xb0 = *(const bf16x8*)xn;
      xb1 = *(const bf16x8*)(xn + 8);
    }
    bf16x8 fa[4], fb[4];
#pragma unroll
    for (int i = 0; i < 4; ++i)
      fa[i] = *(const bf16x8*)&As[(mq + i * 16 + col) * 32 + quad * 8];
#pragma unroll
    for (int j = 0; j < 4; ++j)
      fb[j] = *(const bf16x8*)&Bs[(nq + j * 16 + col) * 32 + quad * 8];
#pragma unroll
    for (int i = 0; i < 4; ++i)
#pragma unroll
      for (int j = 0; j < 4; ++j)
        acc[i][j] = __builtin_amdgcn_mfma_f32_16x16x32_bf16(fa[i], fb[j], acc[i][j], 0, 0, 0);
    __syncthreads();
  }
  {
    float* Yf = (float*)Yout + (size_t)b * 256 * 4096;
#pragma unroll
    for (int i = 0; i < 4; ++i) {
#pragma unroll
      for (int r = 0; r < 4; ++r) {
        int o = o0 + mq + i * 16 + quad * 4 + r;
        float scale = bn_g[o] * 0.9999950000374997f;  // rsqrt(1 + 1e-5)
        float shift = bn_b[o];
        float* yrow = Yf + (size_t)o * 4096 + n0 + nq + col;
#pragma unroll
        for (int j = 0; j < 4; ++j) yrow[j * 16] = acc[i][j][r] * scale + shift;
      }
    }
  }
}

// ------- K5: na2d AV with LDS-staged XT slab; bf16 attn input -------
template <int KK>
DEV void na2d_body(const __bf16* __restrict__ attnL, const __bf16* __restrict__ XT,
                   __bf16* __restrict__ midT, __bf16* xs, int bg, int h0, int chalf, int t) {
  constexpr int CNT = KK * KK, KC = KK / 2, SMAX = 64 - KK;
  constexpr int ROWS = KK + 3;
  constexpr int PW = (KK == 5) ? 32 : 56;
  int b = bg >> 2, g = bg & 3;
  int si0 = min(max(h0 - KC, 0), SMAX);
  {
    int sn = t >> 2, sc = t & 3;
    const __bf16* src = XT + ((size_t)b * 4096 + sn) * 256 + g * 64 + chalf * 32 + sc * 8;
#pragma unroll
    for (int r = 0; r < ROWS; ++r) {
      int gr = min(si0 + r, 63);
      *(bf16x8*)&xs[(r * 64 + sn) * 40 + sc * 8] = *(const bf16x8*)(src + (size_t)gr * 64 * 256);
    }
  }
  __syncthreads();
  int w = t >> 2, cg = t & 3;
  int sj = min(max(w - KC, 0), SMAX);
#pragma unroll
  for (int h4 = 0; h4 < 4; ++h4) {
    int h = h0 + h4;
    int base = min(max(h - KC, 0), SMAX) - si0;
    bf16x8 avh[PW / 8];
    const __bf16* ap = attnL + ((size_t)bg * 4096 + h * 64 + w) * 56;
#pragma unroll
    for (int i = 0; i < PW / 8; ++i) avh[i] = *(const bf16x8*)(ap + i * 8);
    float av[CNT];
#pragma unroll
    for (int m = 0; m < CNT; ++m) av[m] = (float)avh[m / 8][m % 8];
    float acc[8] = {};
#pragma unroll
    for (int p = 0; p < KK; ++p) {
      const __bf16* xr = &xs[((base + p) * 64 + sj) * 40 + cg * 8];
#pragma unroll
      for (int q = 0; q < KK; ++q) {
        bf16x8 v = *(const bf16x8*)(xr + q * 40);
        float a = av[p * KK + q];
#pragma unroll
        for (int e = 0; e < 8; ++e) acc[e] += a * (float)v[e];
      }
    }
    __bf16 hv[8];
#pragma unroll
    for (int e = 0; e < 8; ++e) hv[e] = (__bf16)acc[e];
    *(bf16x8*)&midT[((size_t)bg * 4096 + h * 64 + w) * 64 + chalf * 32 + cg * 8] = *(bf16x8*)hv;
  }
}

__global__ __launch_bounds__(256)
void na2d_kernel(const __bf16* __restrict__ attnL, const __bf16* __restrict__ XT,
                 __bf16* __restrict__ midT) {
  __shared__ __bf16 xs[10 * 64 * 40];   // 51.2 KB
  int bg = blockIdx.x, h0 = blockIdx.y * 4, chalf = blockIdx.z, t = threadIdx.x;
  if ((bg & 3) < 2) na2d_body<5>(attnL, XT, midT, xs, bg, h0, chalf, t);
  else              na2d_body<7>(attnL, XT, midT, xs, bg, h0, chalf, t);
}

// ---------------- launch ----------------
extern "C" void kernel_launch(void* const* d_in, const int* in_sizes, int n_in,
                              void* d_out, int out_size, void* d_ws, size_t ws_size,
                              hipStream_t stream) {
  const float* x     = (const float*)d_in[0];
  const float* ctx   = (const float*)d_in[1];
  const float* Wq    = (const float*)d_in[2];
  const float* gq    = (const float*)d_in[3];
  const float* bq    = (const float*)d_in[4];
  const float* Wk    = (const float*)d_in[5];
  const float* gk    = (const float*)d_in[6];
  const float* bk    = (const float*)d_in[7];
  const float* Wproj = (const float*)d_in[8];
  const float* rpb1  = (const float*)d_in[9];
  const float* rpb2  = (const float*)d_in[10];
  const float* Wdy   = (const float*)d_in[11];
  const float* bn_g  = (const float*)d_in[12];
  const float* bn_b  = (const float*)d_in[13];
  float* out = (float*)d_out;

  float* ws     = (float*)d_ws;
  float* kctx   = ws;                          // 50176 f
  float* kf     = kctx + 50176;                // 50176 f
  __bf16* attnL = (__bf16*)(kf + 50176);       // 16*4096*56 = 3670016 bf16
  __bf16* wqb   = attnL + 3670016;             // 65536 bf16
  __bf16* wdyb  = wqb + 65536;                 // 65536 bf16
  __bf16* kfpT  = wdyb + 65536;                // 16*80*64 = 81920 bf16
  __bf16* XT    = kfpT + 81920;                // 4194304 bf16
  __bf16* midT  = XT + 4194304;                // 4194304 bf16 (planar [bg][n][64])

  prep_kernel<<<dim3(1536), dim3(256), 0, stream>>>(Wq, Wdy, ctx, x, wqb, wdyb, kctx, XT);
  kf_ln_kernel<<<dim3(196), dim3(256), 0, stream>>>(kctx, Wk, gk, bk, kf);
  kfp_kernel<<<dim3(16, 5), dim3(256), 0, stream>>>(kf, Wproj, kfpT);
  qattn_kernel<<<dim3(128, 1, 4), dim3(256), 0, stream>>>(wqb, XT, kfpT, gq, bq, rpb1, rpb2, attnL);
  na2d_kernel<<<dim3(16, 16, 2), dim3(256), 0, stream>>>(attnL, XT, midT);
  conv_mfma_kernel<1><<<dim3(32, 2, 4), dim3(256), 0, stream>>>(wdyb, midT, out, nullptr, bn_g, bn_b);
}

// Round 4
// 160.526 us; speedup vs baseline: 1.0212x; 1.0212x over previous
//
#include <hip/hip_runtime.h>

#define DEV __device__ __forceinline__

typedef __bf16 bf16x8 __attribute__((ext_vector_type(8)));
typedef __bf16 bf16x4 __attribute__((ext_vector_type(4)));
typedef float floatx4 __attribute__((ext_vector_type(4)));

// ---------------- K0: fused prep: cvt weights + pool ctx + transpose x ----
__global__ __launch_bounds__(256)
void prep_kernel(const float* __restrict__ Wq, const float* __restrict__ Wdy,
                 const float* __restrict__ ctx, const float* __restrict__ x,
                 __bf16* __restrict__ wqb, __bf16* __restrict__ wdyb,
                 float* __restrict__ kctx, __bf16* __restrict__ xt) {
  __shared__ float tile[64][65];
  int bid = blockIdx.x, t = threadIdx.x;
  if (bid < 256) {                       // weight cvt
    int i = bid * 256 + t;
    wqb[i]  = (__bf16)Wq[i];
    wdyb[i] = (__bf16)Wdy[i];
  } else if (bid < 512) {                // pool ctx 56x56 -> 7x7, one wave per (b,c)
    int bc = (bid - 256) * 4 + (t >> 6);
    const float* src = ctx + (size_t)bc * (56 * 56);
    int w = t & 63;
#pragma unroll
    for (int pi = 0; pi < 7; ++pi) {
      float s = 0.f;
      if (w < 56) {
#pragma unroll
        for (int di = 0; di < 8; ++di) s += src[(pi * 8 + di) * 56 + w];
      }
      s += __shfl_down(s, 4);
      s += __shfl_down(s, 2);
      s += __shfl_down(s, 1);
      if (w < 56 && (w & 7) == 0)
        kctx[(size_t)bc * 49 + pi * 7 + (w >> 3)] = s * (1.f / 64.f);
    }
  } else {                               // XT[b][n][c] = bf16(x[b][c][n])
    int idx = bid - 512;
    int b = idx >> 8, c0 = ((idx >> 6) & 3) * 64, n0 = (idx & 63) * 64;
    int lane = t & 63, rg = t >> 6;
    const float* src = x + ((size_t)b * 256 + c0) * 4096 + n0;
    for (int i = rg; i < 64; i += 4) tile[i][lane] = src[(size_t)i * 4096 + lane];
    __syncthreads();
    __bf16* dst = xt + ((size_t)b * 4096 + n0) * 256 + c0;
    for (int i = rg; i < 64; i += 4) dst[(size_t)i * 256 + lane] = (__bf16)tile[lane][i];
  }
}

// ---------------- K2: kf = LN(Wk @ kctx) per (b,l) ----------------
__global__ __launch_bounds__(256)
void kf_ln_kernel(const float* __restrict__ kctx, const float* __restrict__ Wk,
                  const float* __restrict__ gk, const float* __restrict__ bk,
                  float* __restrict__ kf) {
  int b = blockIdx.x / 49, l = blockIdx.x % 49;
  __shared__ float xs[256];
  __shared__ float r1[4], r2[4];
  int o = threadIdx.x;
  xs[o] = kctx[((size_t)b * 256 + o) * 49 + l];
  __syncthreads();
  const float* wrow = Wk + (size_t)o * 256;
  float acc = 0.f;
#pragma unroll 8
  for (int c = 0; c < 256; c += 4) {
    float4 wv = *(const float4*)(wrow + c);
    acc += wv.x * xs[c] + wv.y * xs[c + 1] + wv.z * xs[c + 2] + wv.w * xs[c + 3];
  }
  float s1 = acc, s2 = acc * acc;
#pragma unroll
  for (int off = 32; off > 0; off >>= 1) {
    s1 += __shfl_down(s1, off);
    s2 += __shfl_down(s2, off);
  }
  int wv_ = o >> 6, ln = o & 63;
  if (ln == 0) { r1[wv_] = s1; r2[wv_] = s2; }
  __syncthreads();
  float mu  = (r1[0] + r1[1] + r1[2] + r1[3]) * (1.f / 256.f);
  float var = (r2[0] + r2[1] + r2[2] + r2[3]) * (1.f / 256.f) - mu * mu;
  float rstd = rsqrtf(var + 1e-6f);
  kf[((size_t)b * 256 + o) * 49 + l] = (acc - mu) * rstd * gk[o] + bk[o];
}

// ------- K2b: kfpT[bg][m(80)][d(64)] = bf16( sum_l kf[b][g*64+d][l] * Wproj[m][l] ) -------
__global__ __launch_bounds__(256)
void kfp_kernel(const float* __restrict__ kf, const float* __restrict__ Wproj,
                __bf16* __restrict__ kfpT) {
  int bg = blockIdx.x; int b = bg >> 2, g = bg & 3;
  int m0 = blockIdx.y * 16;
  __shared__ float kfs[64][50];
  __shared__ float wps[16][50];
  int t = threadIdx.x;
  for (int i = t; i < 64 * 49; i += 256) {
    int d = i / 49, l = i % 49;
    kfs[d][l] = kf[((size_t)b * 256 + g * 64 + d) * 49 + l];
  }
  for (int i = t; i < 16 * 49; i += 256) {
    int m = i / 49, l = i % 49;
    wps[m][l] = (m0 + m < 74) ? Wproj[(m0 + m) * 49 + l] : 0.f;
  }
  __syncthreads();
  for (int i = t; i < 64 * 16; i += 256) {
    int d = i >> 4, m = i & 15;
    float s = 0.f;
    if (m0 + m < 74) {
#pragma unroll 7
      for (int l = 0; l < 49; ++l) s += kfs[d][l] * wps[m][l];
    }
    kfpT[(size_t)bg * 5120 + (m0 + m) * 64 + d] = (__bf16)s;
  }
}

// ---------------- softmax helpers (unchanged, proven) ----------------
DEV int rep_idx(int p, int kc, int t1, int sub) {
  return p < kc ? p : (p < t1 ? kc : p - sub);
}

template <int KK>
DEV void softmax_write(const float* wms, const float* rpb_s, __bf16* __restrict__ attnL,
                       int bg, int n_glob, int row) {
  constexpr int CNT = KK * KK;
  constexpr int RS  = 2 * KK - 1;
  constexpr int KC  = KK / 2;
  constexpr int T1  = KC + (64 - KK + 1);
  constexpr int SUB = 64 - KK;
  constexpr int MLO = (KK == 5) ? 0 : 25;
  constexpr int PW  = (KK == 5) ? 32 : 56;    // padded width (multiple of 8)
  int h = n_glob >> 6, w = n_glob & 63;
  int rh = rep_idx(63 - h, KC, T1, SUB);
  int rw = rep_idx(63 - w, KC, T1, SUB);
  float vals[CNT];
  float mx = -1e30f;
#pragma unroll
  for (int m = 0; m < CNT; ++m) {
    int ki = m / KK, kj = m % KK;
    float v = wms[row * 81 + MLO + m] + rpb_s[(rh + ki) * RS + rw + kj];
    vals[m] = v; mx = fmaxf(mx, v);
  }
  float ssum = 0.f;
#pragma unroll
  for (int m = 0; m < CNT; ++m) { float e = __expf(vals[m] - mx); vals[m] = e; ssum += e; }
  float inv = 1.f / ssum;
  __bf16 hv[PW];
#pragma unroll
  for (int m = 0; m < PW; ++m) hv[m] = (__bf16)(m < CNT ? vals[m] * inv : 0.f);
  __bf16* ap = attnL + ((size_t)bg * 4096 + n_glob) * 56;
#pragma unroll
  for (int i = 0; i < PW / 8; ++i) *(bf16x8*)(ap + i * 8) = *(bf16x8*)&hv[i * 8];
}

// ---------------- K3: fused q-GEMM + LN + QK-proj MFMA + softmax (512 thr, 8 waves) ----
// Block = (64-n tile, b), 8 waves = 2 waves/SIMD for latency co-scheduling.
// Wave wv: o-quadrant oq = wv&3, n-half nh = wv>>2 (32 n each).
// Phase 1: 256x64x256 bf16 MFMA GEMM (q = Wq @ x), reg-prefetched K-loop.
// Phase 2: LN over o per n, exact f32 (red[4 oq][64 n] cross-wave reduce).
// Phase 3: q-hat -> Aat A-fragments; attn MFMA (2 waves per head-group g).
// Phase 4: rpb + softmax, rows 0..255 on t<256.
__global__ __launch_bounds__(512, 1)
void qattn_kernel(const __bf16* __restrict__ Wb, const __bf16* __restrict__ XT,
                  const __bf16* __restrict__ kfpT,
                  const float* __restrict__ gq, const float* __restrict__ bq,
                  const float* __restrict__ rpb1, const float* __restrict__ rpb2,
                  __bf16* __restrict__ attnL) {
  __shared__ float wms[256 * 81];        // 82.9 KB, overlaid: As/Bs -> Aat -> wms
  __shared__ float rpb_s[500];           // rpb1 [0..161], rpb2 [162..499]
  __shared__ float gqs[256], bqs[256];
  __shared__ float red_s[4][64], red_q[4][64];
  __shared__ float st_mu[64], st_rs[64];
  __bf16* As  = (__bf16*)wms;            // [256 o][32 k] = 16384 B
  __bf16* Bs  = (__bf16*)wms + 8192;     // [64 n][32 k]  = 4096 B
  __bf16* Aat = (__bf16*)wms;            // [4 g][64 n][72 d] = 36864 B

  int b  = blockIdx.z;
  int n0 = blockIdx.x * 64;
  int t  = threadIdx.x;
  int lane = t & 63, wv = t >> 6;
  int oq = wv & 3, nh = wv >> 2;         // o-quadrant, n-half
  int col = lane & 15, quad = lane >> 4;

  if (t < 256) {
    gqs[t] = gq[t] * 0.125f;             // SCALE folded
    bqs[t] = bq[t] * 0.125f;
  }
  for (int i = t; i < 162; i += 512) rpb_s[i] = rpb1[i];
  for (int i = t; i < 338; i += 512) rpb_s[162 + i] = rpb2[i];

  // ---- phase 1: q = Wq @ x, M=256(o) x N=64(n) x K=256, reg-prefetched ----
  floatx4 acc[4][2];
#pragma unroll
  for (int i = 0; i < 4; ++i)
#pragma unroll
    for (int j = 0; j < 2; ++j) acc[i][j] = {0.f, 0.f, 0.f, 0.f};

  int rowA = t >> 1, halfA = (t & 1) * 16;     // 256 W rows, 16 elems each
  int rowB = t >> 3, kB = (t & 7) * 4;         // 64 XT rows, 4 elems each
  const __bf16* wp = Wb + (size_t)rowA * 256 + halfA;
  const __bf16* xp = XT + ((size_t)b * 4096 + n0 + rowB) * 256 + kB;
  bf16x8 ra0 = *(const bf16x8*)wp;
  bf16x8 ra1 = *(const bf16x8*)(wp + 8);
  bf16x4 rb  = *(const bf16x4*)xp;

  for (int c0 = 0; c0 < 256; c0 += 32) {
    *(bf16x8*)&As[rowA * 32 + halfA]     = ra0;
    *(bf16x8*)&As[rowA * 32 + halfA + 8] = ra1;
    *(bf16x4*)&Bs[rowB * 32 + kB]        = rb;
    __syncthreads();
    if (c0 + 32 < 256) {                 // prefetch next K-tile; hides under MFMA
      ra0 = *(const bf16x8*)(wp + c0 + 32);
      ra1 = *(const bf16x8*)(wp + c0 + 40);
      rb  = *(const bf16x4*)(xp + c0 + 32);
    }
    bf16x8 fa[4], fb[2];
#pragma unroll
    for (int i = 0; i < 4; ++i)
      fa[i] = *(const bf16x8*)&As[(oq * 64 + i * 16 + col) * 32 + quad * 8];
#pragma unroll
    for (int j = 0; j < 2; ++j)
      fb[j] = *(const bf16x8*)&Bs[(nh * 32 + j * 16 + col) * 32 + quad * 8];
#pragma unroll
    for (int i = 0; i < 4; ++i)
#pragma unroll
      for (int j = 0; j < 2; ++j)
        acc[i][j] = __builtin_amdgcn_mfma_f32_16x16x32_bf16(fa[i], fb[j], acc[i][j], 0, 0, 0);
    __syncthreads();
  }

  // ---- phase 2: LN stats over o (exact f32) ----
  // lane holds o = oq*64 + i*16 + quad*4 + r ; n_loc = nh*32 + j*16 + col
#pragma unroll
  for (int j = 0; j < 2; ++j) {
    float s = 0.f, q = 0.f;
#pragma unroll
    for (int i = 0; i < 4; ++i)
#pragma unroll
      for (int r = 0; r < 4; ++r) { float v = acc[i][j][r]; s += v; q += v * v; }
    s += __shfl_xor(s, 16); s += __shfl_xor(s, 32);   // reduce over quad -> full 64-o
    q += __shfl_xor(q, 16); q += __shfl_xor(q, 32);
    if (quad == 0) {
      red_s[oq][nh * 32 + j * 16 + col] = s;
      red_q[oq][nh * 32 + j * 16 + col] = q;
    }
  }
  __syncthreads();
  if (t < 64) {
    float s = red_s[0][t] + red_s[1][t] + red_s[2][t] + red_s[3][t];
    float q = red_q[0][t] + red_q[1][t] + red_q[2][t] + red_q[3][t];
    float mu  = s * (1.f / 256.f);
    float var = q * (1.f / 256.f) - mu * mu;
    st_mu[t] = mu;
    st_rs[t] = rsqrtf(var + 1e-6f);
  }
  __syncthreads();

  // ---- phase 3: q-hat -> Aat (A-fragment layout), then attn MFMA ----
#pragma unroll
  for (int j = 0; j < 2; ++j) {
    int n_loc = nh * 32 + j * 16 + col;
    float mu = st_mu[n_loc], rs = st_rs[n_loc];
#pragma unroll
    for (int i = 0; i < 4; ++i) {
      __bf16 pk[4];
#pragma unroll
      for (int r = 0; r < 4; ++r) {
        int o = oq * 64 + i * 16 + quad * 4 + r;
        pk[r] = (__bf16)((acc[i][j][r] - mu) * rs * gqs[o] + bqs[o]);
      }
      *(bf16x4*)&Aat[((size_t)(oq * 64 + n_loc)) * 72 + i * 16 + quad * 4] = *(bf16x4*)pk;
    }
  }
  __syncthreads();

  // attn MFMA: per head-group g = oq; 2 waves/g, each 32 n x 80 m x K=64
  bf16x8 fa2[2][2], fb2[2][5];
  const __bf16* kp = kfpT + (size_t)(b * 4 + oq) * 5120;   // L2-hot, 10 KB
#pragma unroll
  for (int ks = 0; ks < 2; ++ks) {
#pragma unroll
    for (int a = 0; a < 2; ++a)
      fa2[ks][a] = *(const bf16x8*)&Aat[((size_t)(oq * 64 + nh * 32 + a * 16 + col)) * 72 + ks * 32 + quad * 8];
#pragma unroll
    for (int nt = 0; nt < 5; ++nt)
      fb2[ks][nt] = *(const bf16x8*)&kp[(nt * 16 + col) * 64 + ks * 32 + quad * 8];
  }
  floatx4 acc2[2][5];
#pragma unroll
  for (int a = 0; a < 2; ++a)
#pragma unroll
    for (int nt = 0; nt < 5; ++nt) acc2[a][nt] = {0.f, 0.f, 0.f, 0.f};
#pragma unroll
  for (int ks = 0; ks < 2; ++ks)
#pragma unroll
    for (int a = 0; a < 2; ++a)
#pragma unroll
      for (int nt = 0; nt < 5; ++nt)
        acc2[a][nt] = __builtin_amdgcn_mfma_f32_16x16x32_bf16(fa2[ks][a], fb2[ks][nt], acc2[a][nt], 0, 0, 0);
  __syncthreads();   // all Aat reads done before wms overwrite

  // wgt rows: row = g*64 + n_loc (0..255)
#pragma unroll
  for (int a = 0; a < 2; ++a)
#pragma unroll
    for (int nt = 0; nt < 5; ++nt)
#pragma unroll
      for (int r = 0; r < 4; ++r)
        wms[(oq * 64 + nh * 32 + a * 16 + quad * 4 + r) * 81 + nt * 16 + col] = acc2[a][nt][r];
  __syncthreads();

  // ---- phase 4: softmax, one row per thread (256 rows = 64 n x 4 g) ----
  if (t < 256) {
    int g2 = t >> 6;
    int n_glob = n0 + (t & 63);
    int bg = b * 4 + g2;
    if (g2 < 2) softmax_write<5>(wms, rpb_s + g2 * 81,              attnL, bg, n_glob, t);
    else        softmax_write<7>(wms, rpb_s + 162 + (g2 - 2) * 169, attnL, bg, n_glob, t);
  }
}

// ---------------- K-out: bf16 MFMA 1x1 conv, reg-prefetched K-loop ----------------
// MODE 1: B = midT planar [b*4+g][n][64]; out fp32 [o][n] + BN affine.
template <int MODE>
__global__ __launch_bounds__(256, 2)
void conv_mfma_kernel(const __bf16* __restrict__ Wb, const __bf16* __restrict__ Xin,
                      void* __restrict__ Yout, float* __restrict__ stats,
                      const float* __restrict__ bn_g, const float* __restrict__ bn_b) {
  int b  = blockIdx.z;
  int n0 = blockIdx.x * 128;
  int o0 = blockIdx.y * 128;
  __shared__ __bf16 As[128 * 32];   // [m][k]
  __shared__ __bf16 Bs[128 * 32];   // [n][k]
  int t = threadIdx.x;
  int lane = t & 63, wv = t >> 6;
  int mq = (wv & 1) * 64, nq = (wv >> 1) * 64;
  int col = lane & 15, quad = lane >> 4;
  floatx4 acc[4][4];
#pragma unroll
  for (int i = 0; i < 4; ++i)
#pragma unroll
    for (int j = 0; j < 4; ++j) acc[i][j] = {0.f, 0.f, 0.f, 0.f};
  int sm = t >> 1, sk = (t & 1) << 4;
  const __bf16* wp = Wb + (size_t)(o0 + sm) * 256 + sk;
  auto xaddr = [&](int c0) -> const __bf16* {
    if (MODE == 0) {
      return Xin + ((size_t)b * 4096 + n0 + sm) * 256 + c0 + sk;
    } else {
      int c = c0 + sk, g = c >> 6, c64 = c & 63;   // 16-elem load stays in-plane
      return Xin + (((size_t)(b * 4 + g)) * 4096 + n0 + sm) * 64 + c64;
    }
  };
  bf16x8 wa0 = *(const bf16x8*)wp;
  bf16x8 wa1 = *(const bf16x8*)(wp + 8);
  const __bf16* x0 = xaddr(0);
  bf16x8 xb0 = *(const bf16x8*)x0;
  bf16x8 xb1 = *(const bf16x8*)(x0 + 8);
  for (int c0 = 0; c0 < 256; c0 += 32) {
    *(bf16x8*)&As[sm * 32 + sk]     = wa0;
    *(bf16x8*)&As[sm * 32 + sk + 8] = wa1;
    *(bf16x8*)&Bs[sm * 32 + sk]     = xb0;
    *(bf16x8*)&Bs[sm * 32 + sk + 8] = xb1;
    __syncthreads();
    if (c0 + 32 < 256) {               // prefetch next K-tile; hides under MFMA
      wa0 = *(const bf16x8*)(wp + c0 + 32);
      wa1 = *(const bf16x8*)(wp + c0 + 40);
      const __bf16* xn = xaddr(c0 + 32);
      xb0 = *(const bf16x8*)xn;
      xb1 = *(const bf16x8*)(xn + 8);
    }
    bf16x8 fa[4], fb[4];
#pragma unroll
    for (int i = 0; i < 4; ++i)
      fa[i] = *(const bf16x8*)&As[(mq + i * 16 + col) * 32 + quad * 8];
#pragma unroll
    for (int j = 0; j < 4; ++j)
      fb[j] = *(const bf16x8*)&Bs[(nq + j * 16 + col) * 32 + quad * 8];
#pragma unroll
    for (int i = 0; i < 4; ++i)
#pragma unroll
      for (int j = 0; j < 4; ++j)
        acc[i][j] = __builtin_amdgcn_mfma_f32_16x16x32_bf16(fa[i], fb[j], acc[i][j], 0, 0, 0);
    __syncthreads();
  }
  {
    float* Yf = (float*)Yout + (size_t)b * 256 * 4096;
#pragma unroll
    for (int i = 0; i < 4; ++i) {
#pragma unroll
      for (int r = 0; r < 4; ++r) {
        int o = o0 + mq + i * 16 + quad * 4 + r;
        float scale = bn_g[o] * 0.9999950000374997f;  // rsqrt(1 + 1e-5)
        float shift = bn_b[o];
        float* yrow = Yf + (size_t)o * 4096 + n0 + nq + col;
#pragma unroll
        for (int j = 0; j < 4; ++j) yrow[j * 16] = acc[i][j][r] * scale + shift;
      }
    }
  }
}

// ------- K5: na2d AV with LDS-staged XT slab; bf16 attn input -------
template <int KK>
DEV void na2d_body(const __bf16* __restrict__ attnL, const __bf16* __restrict__ XT,
                   __bf16* __restrict__ midT, __bf16* xs, int bg, int h0, int chalf, int t) {
  constexpr int CNT = KK * KK, KC = KK / 2, SMAX = 64 - KK;
  constexpr int ROWS = KK + 3;
  constexpr int PW = (KK == 5) ? 32 : 56;
  int b = bg >> 2, g = bg & 3;
  int si0 = min(max(h0 - KC, 0), SMAX);
  {
    int sn = t >> 2, sc = t & 3;
    const __bf16* src = XT + ((size_t)b * 4096 + sn) * 256 + g * 64 + chalf * 32 + sc * 8;
#pragma unroll
    for (int r = 0; r < ROWS; ++r) {
      int gr = min(si0 + r, 63);
      *(bf16x8*)&xs[(r * 64 + sn) * 40 + sc * 8] = *(const bf16x8*)(src + (size_t)gr * 64 * 256);
    }
  }
  __syncthreads();
  int w = t >> 2, cg = t & 3;
  int sj = min(max(w - KC, 0), SMAX);
#pragma unroll
  for (int h4 = 0; h4 < 4; ++h4) {
    int h = h0 + h4;
    int base = min(max(h - KC, 0), SMAX) - si0;
    bf16x8 avh[PW / 8];
    const __bf16* ap = attnL + ((size_t)bg * 4096 + h * 64 + w) * 56;
#pragma unroll
    for (int i = 0; i < PW / 8; ++i) avh[i] = *(const bf16x8*)(ap + i * 8);
    float av[CNT];
#pragma unroll
    for (int m = 0; m < CNT; ++m) av[m] = (float)avh[m / 8][m % 8];
    float acc[8] = {};
#pragma unroll
    for (int p = 0; p < KK; ++p) {
      const __bf16* xr = &xs[((base + p) * 64 + sj) * 40 + cg * 8];
#pragma unroll
      for (int q = 0; q < KK; ++q) {
        bf16x8 v = *(const bf16x8*)(xr + q * 40);
        float a = av[p * KK + q];
#pragma unroll
        for (int e = 0; e < 8; ++e) acc[e] += a * (float)v[e];
      }
    }
    __bf16 hv[8];
#pragma unroll
    for (int e = 0; e < 8; ++e) hv[e] = (__bf16)acc[e];
    *(bf16x8*)&midT[((size_t)bg * 4096 + h * 64 + w) * 64 + chalf * 32 + cg * 8] = *(bf16x8*)hv;
  }
}

__global__ __launch_bounds__(256)
void na2d_kernel(const __bf16* __restrict__ attnL, const __bf16* __restrict__ XT,
                 __bf16* __restrict__ midT) {
  __shared__ __bf16 xs[10 * 64 * 40];   // 51.2 KB
  int bg = blockIdx.x, h0 = blockIdx.y * 4, chalf = blockIdx.z, t = threadIdx.x;
  if ((bg & 3) < 2) na2d_body<5>(attnL, XT, midT, xs, bg, h0, chalf, t);
  else              na2d_body<7>(attnL, XT, midT, xs, bg, h0, chalf, t);
}

// ---------------- launch ----------------
extern "C" void kernel_launch(void* const* d_in, const int* in_sizes, int n_in,
                              void* d_out, int out_size, void* d_ws, size_t ws_size,
                              hipStream_t stream) {
  const float* x     = (const float*)d_in[0];
  const float* ctx   = (const float*)d_in[1];
  const float* Wq    = (const float*)d_in[2];
  const float* gq    = (const float*)d_in[3];
  const float* bq    = (const float*)d_in[4];
  const float* Wk    = (const float*)d_in[5];
  const float* gk    = (const float*)d_in[6];
  const float* bk    = (const float*)d_in[7];
  const float* Wproj = (const float*)d_in[8];
  const float* rpb1  = (const float*)d_in[9];
  const float* rpb2  = (const float*)d_in[10];
  const float* Wdy   = (const float*)d_in[11];
  const float* bn_g  = (const float*)d_in[12];
  const float* bn_b  = (const float*)d_in[13];
  float* out = (float*)d_out;

  float* ws     = (float*)d_ws;
  float* kctx   = ws;                          // 50176 f
  float* kf     = kctx + 50176;                // 50176 f
  __bf16* attnL = (__bf16*)(kf + 50176);       // 16*4096*56 = 3670016 bf16
  __bf16* wqb   = attnL + 3670016;             // 65536 bf16
  __bf16* wdyb  = wqb + 65536;                 // 65536 bf16
  __bf16* kfpT  = wdyb + 65536;                // 16*80*64 = 81920 bf16
  __bf16* XT    = kfpT + 81920;                // 4194304 bf16
  __bf16* midT  = XT + 4194304;                // 4194304 bf16 (planar [bg][n][64])

  prep_kernel<<<dim3(1536), dim3(256), 0, stream>>>(Wq, Wdy, ctx, x, wqb, wdyb, kctx, XT);
  kf_ln_kernel<<<dim3(196), dim3(256), 0, stream>>>(kctx, Wk, gk, bk, kf);
  kfp_kernel<<<dim3(16, 5), dim3(256), 0, stream>>>(kf, Wproj, kfpT);
  qattn_kernel<<<dim3(64, 1, 4), dim3(512), 0, stream>>>(wqb, XT, kfpT, gq, bq, rpb1, rpb2, attnL);
  na2d_kernel<<<dim3(16, 16, 2), dim3(256), 0, stream>>>(attnL, XT, midT);
  conv_mfma_kernel<1><<<dim3(32, 2, 4), dim3(256), 0, stream>>>(wdyb, midT, out, nullptr, bn_g, bn_b);
}

// Round 5
// 157.894 us; speedup vs baseline: 1.0383x; 1.0167x over previous
//
#include <hip/hip_runtime.h>

#define DEV __device__ __forceinline__

typedef __bf16 bf16x8 __attribute__((ext_vector_type(8)));
typedef __bf16 bf16x4 __attribute__((ext_vector_type(4)));
typedef float floatx4 __attribute__((ext_vector_type(4)));

// ---------------- K0: fused prep: cvt weights + pool ctx + transpose x ----
__global__ __launch_bounds__(256)
void prep_kernel(const float* __restrict__ Wq, const float* __restrict__ Wdy,
                 const float* __restrict__ ctx, const float* __restrict__ x,
                 __bf16* __restrict__ wqb, __bf16* __restrict__ wdyb,
                 float* __restrict__ kctx, __bf16* __restrict__ xt) {
  __shared__ float tile[64][65];
  int bid = blockIdx.x, t = threadIdx.x;
  if (bid < 256) {                       // weight cvt
    int i = bid * 256 + t;
    wqb[i]  = (__bf16)Wq[i];
    wdyb[i] = (__bf16)Wdy[i];
  } else if (bid < 512) {                // pool ctx 56x56 -> 7x7, one wave per (b,c)
    int bc = (bid - 256) * 4 + (t >> 6);
    const float* src = ctx + (size_t)bc * (56 * 56);
    int w = t & 63;
#pragma unroll
    for (int pi = 0; pi < 7; ++pi) {
      float s = 0.f;
      if (w < 56) {
#pragma unroll
        for (int di = 0; di < 8; ++di) s += src[(pi * 8 + di) * 56 + w];
      }
      s += __shfl_down(s, 4);
      s += __shfl_down(s, 2);
      s += __shfl_down(s, 1);
      if (w < 56 && (w & 7) == 0)
        kctx[(size_t)bc * 49 + pi * 7 + (w >> 3)] = s * (1.f / 64.f);
    }
  } else {                               // XT[b][n][c] = bf16(x[b][c][n])
    int idx = bid - 512;
    int b = idx >> 8, c0 = ((idx >> 6) & 3) * 64, n0 = (idx & 63) * 64;
    int lane = t & 63, rg = t >> 6;
    const float* src = x + ((size_t)b * 256 + c0) * 4096 + n0;
    for (int i = rg; i < 64; i += 4) tile[i][lane] = src[(size_t)i * 4096 + lane];
    __syncthreads();
    __bf16* dst = xt + ((size_t)b * 4096 + n0) * 256 + c0;
    for (int i = rg; i < 64; i += 4) dst[(size_t)i * 256 + lane] = (__bf16)tile[lane][i];
  }
}

// ---------------- K2: kf = LN(Wk @ kctx) per (b,l) ----------------
__global__ __launch_bounds__(256)
void kf_ln_kernel(const float* __restrict__ kctx, const float* __restrict__ Wk,
                  const float* __restrict__ gk, const float* __restrict__ bk,
                  float* __restrict__ kf) {
  int b = blockIdx.x / 49, l = blockIdx.x % 49;
  __shared__ float xs[256];
  __shared__ float r1[4], r2[4];
  int o = threadIdx.x;
  xs[o] = kctx[((size_t)b * 256 + o) * 49 + l];
  __syncthreads();
  const float* wrow = Wk + (size_t)o * 256;
  float acc = 0.f;
#pragma unroll 8
  for (int c = 0; c < 256; c += 4) {
    float4 wv = *(const float4*)(wrow + c);
    acc += wv.x * xs[c] + wv.y * xs[c + 1] + wv.z * xs[c + 2] + wv.w * xs[c + 3];
  }
  float s1 = acc, s2 = acc * acc;
#pragma unroll
  for (int off = 32; off > 0; off >>= 1) {
    s1 += __shfl_down(s1, off);
    s2 += __shfl_down(s2, off);
  }
  int wv_ = o >> 6, ln = o & 63;
  if (ln == 0) { r1[wv_] = s1; r2[wv_] = s2; }
  __syncthreads();
  float mu  = (r1[0] + r1[1] + r1[2] + r1[3]) * (1.f / 256.f);
  float var = (r2[0] + r2[1] + r2[2] + r2[3]) * (1.f / 256.f) - mu * mu;
  float rstd = rsqrtf(var + 1e-6f);
  kf[((size_t)b * 256 + o) * 49 + l] = (acc - mu) * rstd * gk[o] + bk[o];
}

// ------- K2b: kfpT[bg][m(80)][d(64)] = bf16( sum_l kf[b][g*64+d][l] * Wproj[m][l] ) -------
__global__ __launch_bounds__(256)
void kfp_kernel(const float* __restrict__ kf, const float* __restrict__ Wproj,
                __bf16* __restrict__ kfpT) {
  int bg = blockIdx.x; int b = bg >> 2, g = bg & 3;
  int m0 = blockIdx.y * 16;
  __shared__ float kfs[64][50];
  __shared__ float wps[16][50];
  int t = threadIdx.x;
  for (int i = t; i < 64 * 49; i += 256) {
    int d = i / 49, l = i % 49;
    kfs[d][l] = kf[((size_t)b * 256 + g * 64 + d) * 49 + l];
  }
  for (int i = t; i < 16 * 49; i += 256) {
    int m = i / 49, l = i % 49;
    wps[m][l] = (m0 + m < 74) ? Wproj[(m0 + m) * 49 + l] : 0.f;
  }
  __syncthreads();
  for (int i = t; i < 64 * 16; i += 256) {
    int d = i >> 4, m = i & 15;
    float s = 0.f;
    if (m0 + m < 74) {
#pragma unroll 7
      for (int l = 0; l < 49; ++l) s += kfs[d][l] * wps[m][l];
    }
    kfpT[(size_t)bg * 5120 + (m0 + m) * 64 + d] = (__bf16)s;
  }
}

// ---------------- softmax helpers (unchanged, proven) ----------------
DEV int rep_idx(int p, int kc, int t1, int sub) {
  return p < kc ? p : (p < t1 ? kc : p - sub);
}

template <int KK>
DEV void softmax_write(const float* wms, const float* rpb_s, __bf16* __restrict__ attnL,
                       int bg, int n_glob, int row) {
  constexpr int CNT = KK * KK;
  constexpr int RS  = 2 * KK - 1;
  constexpr int KC  = KK / 2;
  constexpr int T1  = KC + (64 - KK + 1);
  constexpr int SUB = 64 - KK;
  constexpr int MLO = (KK == 5) ? 0 : 25;
  constexpr int PW  = (KK == 5) ? 32 : 56;    // padded width (multiple of 8)
  int h = n_glob >> 6, w = n_glob & 63;
  int rh = rep_idx(63 - h, KC, T1, SUB);
  int rw = rep_idx(63 - w, KC, T1, SUB);
  float vals[CNT];
  float mx = -1e30f;
#pragma unroll
  for (int m = 0; m < CNT; ++m) {
    int ki = m / KK, kj = m % KK;
    float v = wms[row * 81 + MLO + m] + rpb_s[(rh + ki) * RS + rw + kj];
    vals[m] = v; mx = fmaxf(mx, v);
  }
  float ssum = 0.f;
#pragma unroll
  for (int m = 0; m < CNT; ++m) { float e = __expf(vals[m] - mx); vals[m] = e; ssum += e; }
  float inv = 1.f / ssum;
  __bf16 hv[PW];
#pragma unroll
  for (int m = 0; m < PW; ++m) hv[m] = (__bf16)(m < CNT ? vals[m] * inv : 0.f);
  __bf16* ap = attnL + ((size_t)bg * 4096 + n_glob) * 56;
#pragma unroll
  for (int i = 0; i < PW / 8; ++i) *(bf16x8*)(ap + i * 8) = *(bf16x8*)&hv[i * 8];
}

// ---------------- K3: fused q-GEMM + LN + QK-proj MFMA + softmax (512 thr, 8 waves) ----
__global__ __launch_bounds__(512, 1)
void qattn_kernel(const __bf16* __restrict__ Wb, const __bf16* __restrict__ XT,
                  const __bf16* __restrict__ kfpT,
                  const float* __restrict__ gq, const float* __restrict__ bq,
                  const float* __restrict__ rpb1, const float* __restrict__ rpb2,
                  __bf16* __restrict__ attnL) {
  __shared__ float wms[256 * 81];        // 82.9 KB, overlaid: As/Bs -> Aat -> wms
  __shared__ float rpb_s[500];           // rpb1 [0..161], rpb2 [162..499]
  __shared__ float gqs[256], bqs[256];
  __shared__ float red_s[4][64], red_q[4][64];
  __shared__ float st_mu[64], st_rs[64];
  __bf16* As  = (__bf16*)wms;            // [256 o][32 k] = 16384 B
  __bf16* Bs  = (__bf16*)wms + 8192;     // [64 n][32 k]  = 4096 B
  __bf16* Aat = (__bf16*)wms;            // [4 g][64 n][72 d] = 36864 B

  int b  = blockIdx.z;
  int n0 = blockIdx.x * 64;
  int t  = threadIdx.x;
  int lane = t & 63, wv = t >> 6;
  int oq = wv & 3, nh = wv >> 2;         // o-quadrant, n-half
  int col = lane & 15, quad = lane >> 4;

  if (t < 256) {
    gqs[t] = gq[t] * 0.125f;             // SCALE folded
    bqs[t] = bq[t] * 0.125f;
  }
  for (int i = t; i < 162; i += 512) rpb_s[i] = rpb1[i];
  for (int i = t; i < 338; i += 512) rpb_s[162 + i] = rpb2[i];

  // ---- phase 1: q = Wq @ x, M=256(o) x N=64(n) x K=256, reg-prefetched ----
  floatx4 acc[4][2];
#pragma unroll
  for (int i = 0; i < 4; ++i)
#pragma unroll
    for (int j = 0; j < 2; ++j) acc[i][j] = {0.f, 0.f, 0.f, 0.f};

  int rowA = t >> 1, halfA = (t & 1) * 16;     // 256 W rows, 16 elems each
  int rowB = t >> 3, kB = (t & 7) * 4;         // 64 XT rows, 4 elems each
  const __bf16* wp = Wb + (size_t)rowA * 256 + halfA;
  const __bf16* xp = XT + ((size_t)b * 4096 + n0 + rowB) * 256 + kB;
  bf16x8 ra0 = *(const bf16x8*)wp;
  bf16x8 ra1 = *(const bf16x8*)(wp + 8);
  bf16x4 rb  = *(const bf16x4*)xp;

  for (int c0 = 0; c0 < 256; c0 += 32) {
    *(bf16x8*)&As[rowA * 32 + halfA]     = ra0;
    *(bf16x8*)&As[rowA * 32 + halfA + 8] = ra1;
    *(bf16x4*)&Bs[rowB * 32 + kB]        = rb;
    __syncthreads();
    if (c0 + 32 < 256) {                 // prefetch next K-tile; hides under MFMA
      ra0 = *(const bf16x8*)(wp + c0 + 32);
      ra1 = *(const bf16x8*)(wp + c0 + 40);
      rb  = *(const bf16x4*)(xp + c0 + 32);
    }
    bf16x8 fa[4], fb[2];
#pragma unroll
    for (int i = 0; i < 4; ++i)
      fa[i] = *(const bf16x8*)&As[(oq * 64 + i * 16 + col) * 32 + quad * 8];
#pragma unroll
    for (int j = 0; j < 2; ++j)
      fb[j] = *(const bf16x8*)&Bs[(nh * 32 + j * 16 + col) * 32 + quad * 8];
#pragma unroll
    for (int i = 0; i < 4; ++i)
#pragma unroll
      for (int j = 0; j < 2; ++j)
        acc[i][j] = __builtin_amdgcn_mfma_f32_16x16x32_bf16(fa[i], fb[j], acc[i][j], 0, 0, 0);
    __syncthreads();
  }

  // ---- phase 2: LN stats over o (exact f32) ----
#pragma unroll
  for (int j = 0; j < 2; ++j) {
    float s = 0.f, q = 0.f;
#pragma unroll
    for (int i = 0; i < 4; ++i)
#pragma unroll
      for (int r = 0; r < 4; ++r) { float v = acc[i][j][r]; s += v; q += v * v; }
    s += __shfl_xor(s, 16); s += __shfl_xor(s, 32);   // reduce over quad -> full 64-o
    q += __shfl_xor(q, 16); q += __shfl_xor(q, 32);
    if (quad == 0) {
      red_s[oq][nh * 32 + j * 16 + col] = s;
      red_q[oq][nh * 32 + j * 16 + col] = q;
    }
  }
  __syncthreads();
  if (t < 64) {
    float s = red_s[0][t] + red_s[1][t] + red_s[2][t] + red_s[3][t];
    float q = red_q[0][t] + red_q[1][t] + red_q[2][t] + red_q[3][t];
    float mu  = s * (1.f / 256.f);
    float var = q * (1.f / 256.f) - mu * mu;
    st_mu[t] = mu;
    st_rs[t] = rsqrtf(var + 1e-6f);
  }
  __syncthreads();

  // ---- phase 3: q-hat -> Aat (A-fragment layout), then attn MFMA ----
#pragma unroll
  for (int j = 0; j < 2; ++j) {
    int n_loc = nh * 32 + j * 16 + col;
    float mu = st_mu[n_loc], rs = st_rs[n_loc];
#pragma unroll
    for (int i = 0; i < 4; ++i) {
      __bf16 pk[4];
#pragma unroll
      for (int r = 0; r < 4; ++r) {
        int o = oq * 64 + i * 16 + quad * 4 + r;
        pk[r] = (__bf16)((acc[i][j][r] - mu) * rs * gqs[o] + bqs[o]);
      }
      *(bf16x4*)&Aat[((size_t)(oq * 64 + n_loc)) * 72 + i * 16 + quad * 4] = *(bf16x4*)pk;
    }
  }
  __syncthreads();

  // attn MFMA: per head-group g = oq; 2 waves/g, each 32 n x 80 m x K=64
  bf16x8 fa2[2][2], fb2[2][5];
  const __bf16* kp = kfpT + (size_t)(b * 4 + oq) * 5120;   // L2-hot, 10 KB
#pragma unroll
  for (int ks = 0; ks < 2; ++ks) {
#pragma unroll
    for (int a = 0; a < 2; ++a)
      fa2[ks][a] = *(const bf16x8*)&Aat[((size_t)(oq * 64 + nh * 32 + a * 16 + col)) * 72 + ks * 32 + quad * 8];
#pragma unroll
    for (int nt = 0; nt < 5; ++nt)
      fb2[ks][nt] = *(const bf16x8*)&kp[(nt * 16 + col) * 64 + ks * 32 + quad * 8];
  }
  floatx4 acc2[2][5];
#pragma unroll
  for (int a = 0; a < 2; ++a)
#pragma unroll
    for (int nt = 0; nt < 5; ++nt) acc2[a][nt] = {0.f, 0.f, 0.f, 0.f};
#pragma unroll
  for (int ks = 0; ks < 2; ++ks)
#pragma unroll
    for (int a = 0; a < 2; ++a)
#pragma unroll
      for (int nt = 0; nt < 5; ++nt)
        acc2[a][nt] = __builtin_amdgcn_mfma_f32_16x16x32_bf16(fa2[ks][a], fb2[ks][nt], acc2[a][nt], 0, 0, 0);
  __syncthreads();   // all Aat reads done before wms overwrite

#pragma unroll
  for (int a = 0; a < 2; ++a)
#pragma unroll
    for (int nt = 0; nt < 5; ++nt)
#pragma unroll
      for (int r = 0; r < 4; ++r)
        wms[(oq * 64 + nh * 32 + a * 16 + quad * 4 + r) * 81 + nt * 16 + col] = acc2[a][nt][r];
  __syncthreads();

  // ---- phase 4: softmax, one row per thread (256 rows = 64 n x 4 g) ----
  if (t < 256) {
    int g2 = t >> 6;
    int n_glob = n0 + (t & 63);
    int bg = b * 4 + g2;
    if (g2 < 2) softmax_write<5>(wms, rpb_s + g2 * 81,              attnL, bg, n_glob, t);
    else        softmax_write<7>(wms, rpb_s + 162 + (g2 - 2) * 169, attnL, bg, n_glob, t);
  }
}

// ---------------- K-out: bf16 MFMA 1x1 conv, reg-prefetched K-loop ----------------
template <int MODE>
__global__ __launch_bounds__(256, 2)
void conv_mfma_kernel(const __bf16* __restrict__ Wb, const __bf16* __restrict__ Xin,
                      void* __restrict__ Yout, float* __restrict__ stats,
                      const float* __restrict__ bn_g, const float* __restrict__ bn_b) {
  int b  = blockIdx.z;
  int n0 = blockIdx.x * 128;
  int o0 = blockIdx.y * 128;
  __shared__ __bf16 As[128 * 32];   // [m][k]
  __shared__ __bf16 Bs[128 * 32];   // [n][k]
  int t = threadIdx.x;
  int lane = t & 63, wv = t >> 6;
  int mq = (wv & 1) * 64, nq = (wv >> 1) * 64;
  int col = lane & 15, quad = lane >> 4;
  floatx4 acc[4][4];
#pragma unroll
  for (int i = 0; i < 4; ++i)
#pragma unroll
    for (int j = 0; j < 4; ++j) acc[i][j] = {0.f, 0.f, 0.f, 0.f};
  int sm = t >> 1, sk = (t & 1) << 4;
  const __bf16* wp = Wb + (size_t)(o0 + sm) * 256 + sk;
  auto xaddr = [&](int c0) -> const __bf16* {
    if (MODE == 0) {
      return Xin + ((size_t)b * 4096 + n0 + sm) * 256 + c0 + sk;
    } else {
      int c = c0 + sk, g = c >> 6, c64 = c & 63;   // 16-elem load stays in-plane
      return Xin + (((size_t)(b * 4 + g)) * 4096 + n0 + sm) * 64 + c64;
    }
  };
  bf16x8 wa0 = *(const bf16x8*)wp;
  bf16x8 wa1 = *(const bf16x8*)(wp + 8);
  const __bf16* x0 = xaddr(0);
  bf16x8 xb0 = *(const bf16x8*)x0;
  bf16x8 xb1 = *(const bf16x8*)(x0 + 8);
  for (int c0 = 0; c0 < 256; c0 += 32) {
    *(bf16x8*)&As[sm * 32 + sk]     = wa0;
    *(bf16x8*)&As[sm * 32 + sk + 8] = wa1;
    *(bf16x8*)&Bs[sm * 32 + sk]     = xb0;
    *(bf16x8*)&Bs[sm * 32 + sk + 8] = xb1;
    __syncthreads();
    if (c0 + 32 < 256) {               // prefetch next K-tile; hides under MFMA
      wa0 = *(const bf16x8*)(wp + c0 + 32);
      wa1 = *(const bf16x8*)(wp + c0 + 40);
      const __bf16* xn = xaddr(c0 + 32);
      xb0 = *(const bf16x8*)xn;
      xb1 = *(const bf16x8*)(xn + 8);
    }
    bf16x8 fa[4], fb[4];
#pragma unroll
    for (int i = 0; i < 4; ++i)
      fa[i] = *(const bf16x8*)&As[(mq + i * 16 + col) * 32 + quad * 8];
#pragma unroll
    for (int j = 0; j < 4; ++j)
      fb[j] = *(const bf16x8*)&Bs[(nq + j * 16 + col) * 32 + quad * 8];
#pragma unroll
    for (int i = 0; i < 4; ++i)
#pragma unroll
      for (int j = 0; j < 4; ++j)
        acc[i][j] = __builtin_amdgcn_mfma_f32_16x16x32_bf16(fa[i], fb[j], acc[i][j], 0, 0, 0);
    __syncthreads();
  }
  {
    float* Yf = (float*)Yout + (size_t)b * 256 * 4096;
#pragma unroll
    for (int i = 0; i < 4; ++i) {
#pragma unroll
      for (int r = 0; r < 4; ++r) {
        int o = o0 + mq + i * 16 + quad * 4 + r;
        float scale = bn_g[o] * 0.9999950000374997f;  // rsqrt(1 + 1e-5)
        float shift = bn_b[o];
        float* yrow = Yf + (size_t)o * 4096 + n0 + nq + col;
#pragma unroll
        for (int j = 0; j < 4; ++j) yrow[j * 16] = acc[i][j][r] * scale + shift;
      }
    }
  }
}

// ------- K5: na2d AV, f32-staged LDS slab (cvt-once), 512 thr / 8-h slab -------
// block = (bg, 8-h slab, ch-half). xs f32 [ROWS<=14][64 w][36(32+4pad) ch].
// thread: w = t&63, cg = (t>>6)&3 (8-ch group), hh = t>>8 (4-h half of slab).
template <int KK>
DEV void na2d_body8(const __bf16* __restrict__ attnL, const __bf16* __restrict__ XT,
                    __bf16* __restrict__ midT, float* xs, int bg, int h0, int chalf, int t) {
  constexpr int CNT = KK * KK, KC = KK / 2, SMAX = 64 - KK;
  constexpr int ROWS = KK + 7;
  constexpr int PW = (KK == 5) ? 32 : 56;
  int b = bg >> 2, g = bg & 3;
  int si0 = min(max(h0 - KC, 0), SMAX);
  // stage ROWS rows of the 32-ch half into LDS as f32 (convert once)
  {
    int sn = t & 63, sc8 = (t >> 6) & 3, rh = t >> 8;
    const __bf16* src = XT + ((size_t)b * 4096 + sn) * 256 + g * 64 + chalf * 32 + sc8 * 8;
    for (int r = rh; r < ROWS; r += 2) {
      int gr = min(si0 + r, 63);
      bf16x8 v = *(const bf16x8*)(src + (size_t)gr * 64 * 256);
      float f[8];
#pragma unroll
      for (int e = 0; e < 8; ++e) f[e] = (float)v[e];
      float* d = &xs[(r * 64 + sn) * 36 + sc8 * 8];
      *(float4*)d       = *(float4*)&f[0];
      *(float4*)(d + 4) = *(float4*)&f[4];
    }
  }
  __syncthreads();
  int w = t & 63, cg = (t >> 6) & 3, hh = t >> 8;
  int sj = min(max(w - KC, 0), SMAX);
#pragma unroll
  for (int h4 = 0; h4 < 4; ++h4) {
    int h = h0 + hh * 4 + h4;
    int base = min(max(h - KC, 0), SMAX) - si0;
    bf16x8 avh[PW / 8];
    const __bf16* ap = attnL + ((size_t)bg * 4096 + h * 64 + w) * 56;
#pragma unroll
    for (int i = 0; i < PW / 8; ++i) avh[i] = *(const bf16x8*)(ap + i * 8);
    float av[CNT];
#pragma unroll
    for (int m = 0; m < CNT; ++m) av[m] = (float)avh[m / 8][m % 8];
    float acc[8] = {};
#pragma unroll
    for (int p = 0; p < KK; ++p) {
      const float* xr = &xs[((base + p) * 64 + sj) * 36 + cg * 8];
#pragma unroll
      for (int q = 0; q < KK; ++q) {
        float4 v0 = *(const float4*)(xr + q * 36);
        float4 v1 = *(const float4*)(xr + q * 36 + 4);
        float a = av[p * KK + q];
        acc[0] += a * v0.x; acc[1] += a * v0.y; acc[2] += a * v0.z; acc[3] += a * v0.w;
        acc[4] += a * v1.x; acc[5] += a * v1.y; acc[6] += a * v1.z; acc[7] += a * v1.w;
      }
    }
    __bf16 hv[8];
#pragma unroll
    for (int e = 0; e < 8; ++e) hv[e] = (__bf16)acc[e];
    *(bf16x8*)&midT[((size_t)bg * 4096 + h * 64 + w) * 64 + chalf * 32 + cg * 8] = *(bf16x8*)hv;
  }
}

__global__ __launch_bounds__(512, 1)
void na2d_kernel(const __bf16* __restrict__ attnL, const __bf16* __restrict__ XT,
                 __bf16* __restrict__ midT) {
  __shared__ float xs[14 * 64 * 36];   // 129 KB (KK=7 uses 14 rows, KK=5 uses 12)
  int bg = blockIdx.x, h0 = blockIdx.y * 8, chalf = blockIdx.z, t = threadIdx.x;
  if ((bg & 3) < 2) na2d_body8<5>(attnL, XT, midT, xs, bg, h0, chalf, t);
  else              na2d_body8<7>(attnL, XT, midT, xs, bg, h0, chalf, t);
}

// ---------------- launch ----------------
extern "C" void kernel_launch(void* const* d_in, const int* in_sizes, int n_in,
                              void* d_out, int out_size, void* d_ws, size_t ws_size,
                              hipStream_t stream) {
  const float* x     = (const float*)d_in[0];
  const float* ctx   = (const float*)d_in[1];
  const float* Wq    = (const float*)d_in[2];
  const float* gq    = (const float*)d_in[3];
  const float* bq    = (const float*)d_in[4];
  const float* Wk    = (const float*)d_in[5];
  const float* gk    = (const float*)d_in[6];
  const float* bk    = (const float*)d_in[7];
  const float* Wproj = (const float*)d_in[8];
  const float* rpb1  = (const float*)d_in[9];
  const float* rpb2  = (const float*)d_in[10];
  const float* Wdy   = (const float*)d_in[11];
  const float* bn_g  = (const float*)d_in[12];
  const float* bn_b  = (const float*)d_in[13];
  float* out = (float*)d_out;

  float* ws     = (float*)d_ws;
  float* kctx   = ws;                          // 50176 f
  float* kf     = kctx + 50176;                // 50176 f
  __bf16* attnL = (__bf16*)(kf + 50176);       // 16*4096*56 = 3670016 bf16
  __bf16* wqb   = attnL + 3670016;             // 65536 bf16
  __bf16* wdyb  = wqb + 65536;                 // 65536 bf16
  __bf16* kfpT  = wdyb + 65536;                // 16*80*64 = 81920 bf16
  __bf16* XT    = kfpT + 81920;                // 4194304 bf16
  __bf16* midT  = XT + 4194304;                // 4194304 bf16 (planar [bg][n][64])

  prep_kernel<<<dim3(1536), dim3(256), 0, stream>>>(Wq, Wdy, ctx, x, wqb, wdyb, kctx, XT);
  kf_ln_kernel<<<dim3(196), dim3(256), 0, stream>>>(kctx, Wk, gk, bk, kf);
  kfp_kernel<<<dim3(16, 5), dim3(256), 0, stream>>>(kf, Wproj, kfpT);
  qattn_kernel<<<dim3(64, 1, 4), dim3(512), 0, stream>>>(wqb, XT, kfpT, gq, bq, rpb1, rpb2, attnL);
  na2d_kernel<<<dim3(16, 8, 2), dim3(512), 0, stream>>>(attnL, XT, midT);
  conv_mfma_kernel<1><<<dim3(32, 2, 4), dim3(256), 0, stream>>>(wdyb, midT, out, nullptr, bn_g, bn_b);
}

// Round 6
// 155.896 us; speedup vs baseline: 1.0516x; 1.0128x over previous
//
#include <hip/hip_runtime.h>

#define DEV __device__ __forceinline__

typedef __bf16 bf16x8 __attribute__((ext_vector_type(8)));
typedef __bf16 bf16x4 __attribute__((ext_vector_type(4)));
typedef float floatx4 __attribute__((ext_vector_type(4)));

// ---------------- K0: fused prep: cvt weights + pool ctx + transpose x ----
__global__ __launch_bounds__(256)
void prep_kernel(const float* __restrict__ Wq, const float* __restrict__ Wdy,
                 const float* __restrict__ ctx, const float* __restrict__ x,
                 __bf16* __restrict__ wqb, __bf16* __restrict__ wdyb,
                 float* __restrict__ kctx, __bf16* __restrict__ xt) {
  __shared__ float tile[64][65];
  int bid = blockIdx.x, t = threadIdx.x;
  if (bid < 256) {                       // weight cvt
    int i = bid * 256 + t;
    wqb[i]  = (__bf16)Wq[i];
    wdyb[i] = (__bf16)Wdy[i];
  } else if (bid < 512) {                // pool ctx 56x56 -> 7x7, one wave per (b,c)
    int bc = (bid - 256) * 4 + (t >> 6);
    const float* src = ctx + (size_t)bc * (56 * 56);
    int w = t & 63;
#pragma unroll
    for (int pi = 0; pi < 7; ++pi) {
      float s = 0.f;
      if (w < 56) {
#pragma unroll
        for (int di = 0; di < 8; ++di) s += src[(pi * 8 + di) * 56 + w];
      }
      s += __shfl_down(s, 4);
      s += __shfl_down(s, 2);
      s += __shfl_down(s, 1);
      if (w < 56 && (w & 7) == 0)
        kctx[(size_t)bc * 49 + pi * 7 + (w >> 3)] = s * (1.f / 64.f);
    }
  } else {                               // XT[b][n][c] = bf16(x[b][c][n])
    int idx = bid - 512;
    int b = idx >> 8, c0 = ((idx >> 6) & 3) * 64, n0 = (idx & 63) * 64;
    int lane = t & 63, rg = t >> 6;
    const float* src = x + ((size_t)b * 256 + c0) * 4096 + n0;
    for (int i = rg; i < 64; i += 4) tile[i][lane] = src[(size_t)i * 4096 + lane];
    __syncthreads();
    __bf16* dst = xt + ((size_t)b * 4096 + n0) * 256 + c0;
    for (int i = rg; i < 64; i += 4) dst[(size_t)i * 256 + lane] = (__bf16)tile[lane][i];
  }
}

// ---------------- K2: kf = LN(Wk @ kctx) per (b,l) ----------------
__global__ __launch_bounds__(256)
void kf_ln_kernel(const float* __restrict__ kctx, const float* __restrict__ Wk,
                  const float* __restrict__ gk, const float* __restrict__ bk,
                  float* __restrict__ kf) {
  int b = blockIdx.x / 49, l = blockIdx.x % 49;
  __shared__ float xs[256];
  __shared__ float r1[4], r2[4];
  int o = threadIdx.x;
  xs[o] = kctx[((size_t)b * 256 + o) * 49 + l];
  __syncthreads();
  const float* wrow = Wk + (size_t)o * 256;
  float acc = 0.f;
#pragma unroll 8
  for (int c = 0; c < 256; c += 4) {
    float4 wv = *(const float4*)(wrow + c);
    acc += wv.x * xs[c] + wv.y * xs[c + 1] + wv.z * xs[c + 2] + wv.w * xs[c + 3];
  }
  float s1 = acc, s2 = acc * acc;
#pragma unroll
  for (int off = 32; off > 0; off >>= 1) {
    s1 += __shfl_down(s1, off);
    s2 += __shfl_down(s2, off);
  }
  int wv_ = o >> 6, ln = o & 63;
  if (ln == 0) { r1[wv_] = s1; r2[wv_] = s2; }
  __syncthreads();
  float mu  = (r1[0] + r1[1] + r1[2] + r1[3]) * (1.f / 256.f);
  float var = (r2[0] + r2[1] + r2[2] + r2[3]) * (1.f / 256.f) - mu * mu;
  float rstd = rsqrtf(var + 1e-6f);
  kf[((size_t)b * 256 + o) * 49 + l] = (acc - mu) * rstd * gk[o] + bk[o];
}

// ------- K2b: kfpT[bg][m(80)][d(64)] = bf16( sum_l kf[b][g*64+d][l] * Wproj[m][l] ) -------
__global__ __launch_bounds__(256)
void kfp_kernel(const float* __restrict__ kf, const float* __restrict__ Wproj,
                __bf16* __restrict__ kfpT) {
  int bg = blockIdx.x; int b = bg >> 2, g = bg & 3;
  int m0 = blockIdx.y * 16;
  __shared__ float kfs[64][50];
  __shared__ float wps[16][50];
  int t = threadIdx.x;
  for (int i = t; i < 64 * 49; i += 256) {
    int d = i / 49, l = i % 49;
    kfs[d][l] = kf[((size_t)b * 256 + g * 64 + d) * 49 + l];
  }
  for (int i = t; i < 16 * 49; i += 256) {
    int m = i / 49, l = i % 49;
    wps[m][l] = (m0 + m < 74) ? Wproj[(m0 + m) * 49 + l] : 0.f;
  }
  __syncthreads();
  for (int i = t; i < 64 * 16; i += 256) {
    int d = i >> 4, m = i & 15;
    float s = 0.f;
    if (m0 + m < 74) {
#pragma unroll 7
      for (int l = 0; l < 49; ++l) s += kfs[d][l] * wps[m][l];
    }
    kfpT[(size_t)bg * 5120 + (m0 + m) * 64 + d] = (__bf16)s;
  }
}

// ---------------- softmax helpers (unchanged, proven) ----------------
DEV int rep_idx(int p, int kc, int t1, int sub) {
  return p < kc ? p : (p < t1 ? kc : p - sub);
}

template <int KK>
DEV void softmax_write(const float* wms, const float* rpb_s, __bf16* __restrict__ attnL,
                       int bg, int n_glob, int row) {
  constexpr int CNT = KK * KK;
  constexpr int RS  = 2 * KK - 1;
  constexpr int KC  = KK / 2;
  constexpr int T1  = KC + (64 - KK + 1);
  constexpr int SUB = 64 - KK;
  constexpr int MLO = (KK == 5) ? 0 : 25;
  constexpr int PW  = (KK == 5) ? 32 : 56;    // padded width (multiple of 8)
  int h = n_glob >> 6, w = n_glob & 63;
  int rh = rep_idx(63 - h, KC, T1, SUB);
  int rw = rep_idx(63 - w, KC, T1, SUB);
  float vals[CNT];
  float mx = -1e30f;
#pragma unroll
  for (int m = 0; m < CNT; ++m) {
    int ki = m / KK, kj = m % KK;
    float v = wms[row * 81 + MLO + m] + rpb_s[(rh + ki) * RS + rw + kj];
    vals[m] = v; mx = fmaxf(mx, v);
  }
  float ssum = 0.f;
#pragma unroll
  for (int m = 0; m < CNT; ++m) { float e = __expf(vals[m] - mx); vals[m] = e; ssum += e; }
  float inv = 1.f / ssum;
  __bf16 hv[PW];
#pragma unroll
  for (int m = 0; m < PW; ++m) hv[m] = (__bf16)(m < CNT ? vals[m] * inv : 0.f);
  __bf16* ap = attnL + ((size_t)bg * 4096 + n_glob) * 56;
#pragma unroll
  for (int i = 0; i < PW / 8; ++i) *(bf16x8*)(ap + i * 8) = *(bf16x8*)&hv[i * 8];
}

// ---------------- K3: fused q-GEMM + LN + QK-proj MFMA + softmax (512 thr, 8 waves) ----
// Phase 1 now BK=64 (4 K-steps, half the barriers, 2x prefetch hiding window).
// As stride 72 elems (144 B): same bank-spread class as proven 32-elem layout.
// k-accumulation order identical to BK=32 -> bit-identical results.
__global__ __launch_bounds__(512, 1)
void qattn_kernel(const __bf16* __restrict__ Wb, const __bf16* __restrict__ XT,
                  const __bf16* __restrict__ kfpT,
                  const float* __restrict__ gq, const float* __restrict__ bq,
                  const float* __restrict__ rpb1, const float* __restrict__ rpb2,
                  __bf16* __restrict__ attnL) {
  __shared__ float wms[256 * 81];        // 82.9 KB, overlaid: As/Bs -> Aat -> wms
  __shared__ float rpb_s[500];           // rpb1 [0..161], rpb2 [162..499]
  __shared__ float gqs[256], bqs[256];
  __shared__ float red_s[4][64], red_q[4][64];
  __shared__ float st_mu[64], st_rs[64];
  __bf16* As  = (__bf16*)wms;            // [256 o][72 k] = 36864 B
  __bf16* Bs  = (__bf16*)wms + 256 * 72; // [64 n][72 k]  = 9216 B  (total 46 KB)
  __bf16* Aat = (__bf16*)wms;            // [4 g][64 n][72 d] = 36864 B

  int b  = blockIdx.z;
  int n0 = blockIdx.x * 64;
  int t  = threadIdx.x;
  int lane = t & 63, wv = t >> 6;
  int oq = wv & 3, nh = wv >> 2;         // o-quadrant, n-half
  int col = lane & 15, quad = lane >> 4;

  if (t < 256) {
    gqs[t] = gq[t] * 0.125f;             // SCALE folded
    bqs[t] = bq[t] * 0.125f;
  }
  for (int i = t; i < 162; i += 512) rpb_s[i] = rpb1[i];
  for (int i = t; i < 338; i += 512) rpb_s[162 + i] = rpb2[i];

  // ---- phase 1: q = Wq @ x, M=256(o) x N=64(n) x K=256, BK=64, reg-prefetched ----
  floatx4 acc[4][2];
#pragma unroll
  for (int i = 0; i < 4; ++i)
#pragma unroll
    for (int j = 0; j < 2; ++j) acc[i][j] = {0.f, 0.f, 0.f, 0.f};

  int rowA = t >> 1, kA = (t & 1) * 32;        // 256 W rows, 32 elems each
  int rowB = t >> 3, kB = (t & 7) * 8;         // 64 XT rows, 8 elems each
  const __bf16* wp = Wb + (size_t)rowA * 256 + kA;
  const __bf16* xp = XT + ((size_t)b * 4096 + n0 + rowB) * 256 + kB;
  bf16x8 ra0 = *(const bf16x8*)wp;
  bf16x8 ra1 = *(const bf16x8*)(wp + 8);
  bf16x8 ra2 = *(const bf16x8*)(wp + 16);
  bf16x8 ra3 = *(const bf16x8*)(wp + 24);
  bf16x8 rb  = *(const bf16x8*)xp;

  for (int c0 = 0; c0 < 256; c0 += 64) {
    *(bf16x8*)&As[rowA * 72 + kA]      = ra0;
    *(bf16x8*)&As[rowA * 72 + kA + 8]  = ra1;
    *(bf16x8*)&As[rowA * 72 + kA + 16] = ra2;
    *(bf16x8*)&As[rowA * 72 + kA + 24] = ra3;
    *(bf16x8*)&Bs[rowB * 72 + kB]      = rb;
    __syncthreads();
    if (c0 + 64 < 256) {                 // prefetch next K-tile; hides under 16 MFMA
      ra0 = *(const bf16x8*)(wp + c0 + 64);
      ra1 = *(const bf16x8*)(wp + c0 + 72);
      ra2 = *(const bf16x8*)(wp + c0 + 80);
      ra3 = *(const bf16x8*)(wp + c0 + 88);
      rb  = *(const bf16x8*)(xp + c0 + 64);
    }
    bf16x8 fa[2][4], fb[2][2];
#pragma unroll
    for (int ks = 0; ks < 2; ++ks) {
#pragma unroll
      for (int i = 0; i < 4; ++i)
        fa[ks][i] = *(const bf16x8*)&As[(oq * 64 + i * 16 + col) * 72 + ks * 32 + quad * 8];
#pragma unroll
      for (int j = 0; j < 2; ++j)
        fb[ks][j] = *(const bf16x8*)&Bs[(nh * 32 + j * 16 + col) * 72 + ks * 32 + quad * 8];
    }
#pragma unroll
    for (int ks = 0; ks < 2; ++ks)
#pragma unroll
      for (int i = 0; i < 4; ++i)
#pragma unroll
        for (int j = 0; j < 2; ++j)
          acc[i][j] = __builtin_amdgcn_mfma_f32_16x16x32_bf16(fa[ks][i], fb[ks][j], acc[i][j], 0, 0, 0);
    __syncthreads();
  }

  // ---- phase 2: LN stats over o (exact f32) ----
#pragma unroll
  for (int j = 0; j < 2; ++j) {
    float s = 0.f, q = 0.f;
#pragma unroll
    for (int i = 0; i < 4; ++i)
#pragma unroll
      for (int r = 0; r < 4; ++r) { float v = acc[i][j][r]; s += v; q += v * v; }
    s += __shfl_xor(s, 16); s += __shfl_xor(s, 32);   // reduce over quad -> full 64-o
    q += __shfl_xor(q, 16); q += __shfl_xor(q, 32);
    if (quad == 0) {
      red_s[oq][nh * 32 + j * 16 + col] = s;
      red_q[oq][nh * 32 + j * 16 + col] = q;
    }
  }
  __syncthreads();
  if (t < 64) {
    float s = red_s[0][t] + red_s[1][t] + red_s[2][t] + red_s[3][t];
    float q = red_q[0][t] + red_q[1][t] + red_q[2][t] + red_q[3][t];
    float mu  = s * (1.f / 256.f);
    float var = q * (1.f / 256.f) - mu * mu;
    st_mu[t] = mu;
    st_rs[t] = rsqrtf(var + 1e-6f);
  }
  __syncthreads();

  // ---- phase 3: q-hat -> Aat (A-fragment layout), then attn MFMA ----
#pragma unroll
  for (int j = 0; j < 2; ++j) {
    int n_loc = nh * 32 + j * 16 + col;
    float mu = st_mu[n_loc], rs = st_rs[n_loc];
#pragma unroll
    for (int i = 0; i < 4; ++i) {
      __bf16 pk[4];
#pragma unroll
      for (int r = 0; r < 4; ++r) {
        int o = oq * 64 + i * 16 + quad * 4 + r;
        pk[r] = (__bf16)((acc[i][j][r] - mu) * rs * gqs[o] + bqs[o]);
      }
      *(bf16x4*)&Aat[((size_t)(oq * 64 + n_loc)) * 72 + i * 16 + quad * 4] = *(bf16x4*)pk;
    }
  }
  __syncthreads();

  // attn MFMA: per head-group g = oq; 2 waves/g, each 32 n x 80 m x K=64
  bf16x8 fa2[2][2], fb2[2][5];
  const __bf16* kp = kfpT + (size_t)(b * 4 + oq) * 5120;   // L2-hot, 10 KB
#pragma unroll
  for (int ks = 0; ks < 2; ++ks) {
#pragma unroll
    for (int a = 0; a < 2; ++a)
      fa2[ks][a] = *(const bf16x8*)&Aat[((size_t)(oq * 64 + nh * 32 + a * 16 + col)) * 72 + ks * 32 + quad * 8];
#pragma unroll
    for (int nt = 0; nt < 5; ++nt)
      fb2[ks][nt] = *(const bf16x8*)&kp[(nt * 16 + col) * 64 + ks * 32 + quad * 8];
  }
  floatx4 acc2[2][5];
#pragma unroll
  for (int a = 0; a < 2; ++a)
#pragma unroll
    for (int nt = 0; nt < 5; ++nt) acc2[a][nt] = {0.f, 0.f, 0.f, 0.f};
#pragma unroll
  for (int ks = 0; ks < 2; ++ks)
#pragma unroll
    for (int a = 0; a < 2; ++a)
#pragma unroll
      for (int nt = 0; nt < 5; ++nt)
        acc2[a][nt] = __builtin_amdgcn_mfma_f32_16x16x32_bf16(fa2[ks][a], fb2[ks][nt], acc2[a][nt], 0, 0, 0);
  __syncthreads();   // all Aat reads done before wms overwrite

#pragma unroll
  for (int a = 0; a < 2; ++a)
#pragma unroll
    for (int nt = 0; nt < 5; ++nt)
#pragma unroll
      for (int r = 0; r < 4; ++r)
        wms[(oq * 64 + nh * 32 + a * 16 + quad * 4 + r) * 81 + nt * 16 + col] = acc2[a][nt][r];
  __syncthreads();

  // ---- phase 4: softmax, one row per thread (256 rows = 64 n x 4 g) ----
  if (t < 256) {
    int g2 = t >> 6;
    int n_glob = n0 + (t & 63);
    int bg = b * 4 + g2;
    if (g2 < 2) softmax_write<5>(wms, rpb_s + g2 * 81,              attnL, bg, n_glob, t);
    else        softmax_write<7>(wms, rpb_s + 162 + (g2 - 2) * 169, attnL, bg, n_glob, t);
  }
}

// ---------------- K-out: bf16 MFMA 1x1 conv, 128x64 tile -> 2 blocks/CU ----------------
// MODE 1: B = midT planar [b*4+g][n][64]; out fp32 [o][n] + BN affine.
template <int MODE>
__global__ __launch_bounds__(256, 2)
void conv_mfma_kernel(const __bf16* __restrict__ Wb, const __bf16* __restrict__ Xin,
                      void* __restrict__ Yout, float* __restrict__ stats,
                      const float* __restrict__ bn_g, const float* __restrict__ bn_b) {
  int b  = blockIdx.z;
  int n0 = blockIdx.x * 64;
  int o0 = blockIdx.y * 128;
  __shared__ __bf16 As[128 * 32];   // [m][k]
  __shared__ __bf16 Bs[64 * 32];    // [n][k]
  int t = threadIdx.x;
  int lane = t & 63, wv = t >> 6;
  int mq = (wv & 1) * 64, nq = (wv >> 1) * 32;
  int col = lane & 15, quad = lane >> 4;
  floatx4 acc[4][2];
#pragma unroll
  for (int i = 0; i < 4; ++i)
#pragma unroll
    for (int j = 0; j < 2; ++j) acc[i][j] = {0.f, 0.f, 0.f, 0.f};
  int sm = t >> 1, sk = (t & 1) << 4;      // A: 128 rows x 16 elems
  int snB = t >> 2, kB8 = (t & 3) * 8;     // B: 64 rows x 8 elems
  const __bf16* wp = Wb + (size_t)(o0 + sm) * 256 + sk;
  auto xaddr = [&](int c0) -> const __bf16* {
    if (MODE == 0) {
      return Xin + ((size_t)b * 4096 + n0 + snB) * 256 + c0 + kB8;
    } else {
      int c = c0 + kB8, g = c >> 6, c64 = c & 63;   // 8-elem load stays in-plane
      return Xin + (((size_t)(b * 4 + g)) * 4096 + n0 + snB) * 64 + c64;
    }
  };
  bf16x8 wa0 = *(const bf16x8*)wp;
  bf16x8 wa1 = *(const bf16x8*)(wp + 8);
  bf16x8 xb0 = *(const bf16x8*)xaddr(0);
  for (int c0 = 0; c0 < 256; c0 += 32) {
    *(bf16x8*)&As[sm * 32 + sk]     = wa0;
    *(bf16x8*)&As[sm * 32 + sk + 8] = wa1;
    *(bf16x8*)&Bs[snB * 32 + kB8]   = xb0;
    __syncthreads();
    if (c0 + 32 < 256) {               // prefetch next K-tile; hides under MFMA
      wa0 = *(const bf16x8*)(wp + c0 + 32);
      wa1 = *(const bf16x8*)(wp + c0 + 40);
      xb0 = *(const bf16x8*)xaddr(c0 + 32);
    }
    bf16x8 fa[4], fb[2];
#pragma unroll
    for (int i = 0; i < 4; ++i)
      fa[i] = *(const bf16x8*)&As[(mq + i * 16 + col) * 32 + quad * 8];
#pragma unroll
    for (int j = 0; j < 2; ++j)
      fb[j] = *(const bf16x8*)&Bs[(nq + j * 16 + col) * 32 + quad * 8];
#pragma unroll
    for (int i = 0; i < 4; ++i)
#pragma unroll
      for (int j = 0; j < 2; ++j)
        acc[i][j] = __builtin_amdgcn_mfma_f32_16x16x32_bf16(fa[i], fb[j], acc[i][j], 0, 0, 0);
    __syncthreads();
  }
  {
    float* Yf = (float*)Yout + (size_t)b * 256 * 4096;
#pragma unroll
    for (int i = 0; i < 4; ++i) {
#pragma unroll
      for (int r = 0; r < 4; ++r) {
        int o = o0 + mq + i * 16 + quad * 4 + r;
        float scale = bn_g[o] * 0.9999950000374997f;  // rsqrt(1 + 1e-5)
        float shift = bn_b[o];
        float* yrow = Yf + (size_t)o * 4096 + n0 + nq + col;
#pragma unroll
        for (int j = 0; j < 2; ++j) yrow[j * 16] = acc[i][j][r] * scale + shift;
      }
    }
  }
}

// ------- K5: na2d AV, f32-staged LDS slab (cvt-once), 512 thr / 8-h slab -------
template <int KK>
DEV void na2d_body8(const __bf16* __restrict__ attnL, const __bf16* __restrict__ XT,
                    __bf16* __restrict__ midT, float* xs, int bg, int h0, int chalf, int t) {
  constexpr int CNT = KK * KK, KC = KK / 2, SMAX = 64 - KK;
  constexpr int ROWS = KK + 7;
  constexpr int PW = (KK == 5) ? 32 : 56;
  int b = bg >> 2, g = bg & 3;
  int si0 = min(max(h0 - KC, 0), SMAX);
  // stage ROWS rows of the 32-ch half into LDS as f32 (convert once)
  {
    int sn = t & 63, sc8 = (t >> 6) & 3, rh = t >> 8;
    const __bf16* src = XT + ((size_t)b * 4096 + sn) * 256 + g * 64 + chalf * 32 + sc8 * 8;
    for (int r = rh; r < ROWS; r += 2) {
      int gr = min(si0 + r, 63);
      bf16x8 v = *(const bf16x8*)(src + (size_t)gr * 64 * 256);
      float f[8];
#pragma unroll
      for (int e = 0; e < 8; ++e) f[e] = (float)v[e];
      float* d = &xs[(r * 64 + sn) * 36 + sc8 * 8];
      *(float4*)d       = *(float4*)&f[0];
      *(float4*)(d + 4) = *(float4*)&f[4];
    }
  }
  __syncthreads();
  int w = t & 63, cg = (t >> 6) & 3, hh = t >> 8;
  int sj = min(max(w - KC, 0), SMAX);
#pragma unroll
  for (int h4 = 0; h4 < 4; ++h4) {
    int h = h0 + hh * 4 + h4;
    int base = min(max(h - KC, 0), SMAX) - si0;
    bf16x8 avh[PW / 8];
    const __bf16* ap = attnL + ((size_t)bg * 4096 + h * 64 + w) * 56;
#pragma unroll
    for (int i = 0; i < PW / 8; ++i) avh[i] = *(const bf16x8*)(ap + i * 8);
    float av[CNT];
#pragma unroll
    for (int m = 0; m < CNT; ++m) av[m] = (float)avh[m / 8][m % 8];
    float acc[8] = {};
#pragma unroll
    for (int p = 0; p < KK; ++p) {
      const float* xr = &xs[((base + p) * 64 + sj) * 36 + cg * 8];
#pragma unroll
      for (int q = 0; q < KK; ++q) {
        float4 v0 = *(const float4*)(xr + q * 36);
        float4 v1 = *(const float4*)(xr + q * 36 + 4);
        float a = av[p * KK + q];
        acc[0] += a * v0.x; acc[1] += a * v0.y; acc[2] += a * v0.z; acc[3] += a * v0.w;
        acc[4] += a * v1.x; acc[5] += a * v1.y; acc[6] += a * v1.z; acc[7] += a * v1.w;
      }
    }
    __bf16 hv[8];
#pragma unroll
    for (int e = 0; e < 8; ++e) hv[e] = (__bf16)acc[e];
    *(bf16x8*)&midT[((size_t)bg * 4096 + h * 64 + w) * 64 + chalf * 32 + cg * 8] = *(bf16x8*)hv;
  }
}

__global__ __launch_bounds__(512, 1)
void na2d_kernel(const __bf16* __restrict__ attnL, const __bf16* __restrict__ XT,
                 __bf16* __restrict__ midT) {
  __shared__ float xs[14 * 64 * 36];   // 129 KB (KK=7 uses 14 rows, KK=5 uses 12)
  int bg = blockIdx.x, h0 = blockIdx.y * 8, chalf = blockIdx.z, t = threadIdx.x;
  if ((bg & 3) < 2) na2d_body8<5>(attnL, XT, midT, xs, bg, h0, chalf, t);
  else              na2d_body8<7>(attnL, XT, midT, xs, bg, h0, chalf, t);
}

// ---------------- launch ----------------
extern "C" void kernel_launch(void* const* d_in, const int* in_sizes, int n_in,
                              void* d_out, int out_size, void* d_ws, size_t ws_size,
                              hipStream_t stream) {
  const float* x     = (const float*)d_in[0];
  const float* ctx   = (const float*)d_in[1];
  const float* Wq    = (const float*)d_in[2];
  const float* gq    = (const float*)d_in[3];
  const float* bq    = (const float*)d_in[4];
  const float* Wk    = (const float*)d_in[5];
  const float* gk    = (const float*)d_in[6];
  const float* bk    = (const float*)d_in[7];
  const float* Wproj = (const float*)d_in[8];
  const float* rpb1  = (const float*)d_in[9];
  const float* rpb2  = (const float*)d_in[10];
  const float* Wdy   = (const float*)d_in[11];
  const float* bn_g  = (const float*)d_in[12];
  const float* bn_b  = (const float*)d_in[13];
  float* out = (float*)d_out;

  float* ws     = (float*)d_ws;
  float* kctx   = ws;                          // 50176 f
  float* kf     = kctx + 50176;                // 50176 f
  __bf16* attnL = (__bf16*)(kf + 50176);       // 16*4096*56 = 3670016 bf16
  __bf16* wqb   = attnL + 3670016;             // 65536 bf16
  __bf16* wdyb  = wqb + 65536;                 // 65536 bf16
  __bf16* kfpT  = wdyb + 65536;                // 16*80*64 = 81920 bf16
  __bf16* XT    = kfpT + 81920;                // 4194304 bf16
  __bf16* midT  = XT + 4194304;                // 4194304 bf16 (planar [bg][n][64])

  prep_kernel<<<dim3(1536), dim3(256), 0, stream>>>(Wq, Wdy, ctx, x, wqb, wdyb, kctx, XT);
  kf_ln_kernel<<<dim3(196), dim3(256), 0, stream>>>(kctx, Wk, gk, bk, kf);
  kfp_kernel<<<dim3(16, 5), dim3(256), 0, stream>>>(kf, Wproj, kfpT);
  qattn_kernel<<<dim3(64, 1, 4), dim3(512), 0, stream>>>(wqb, XT, kfpT, gq, bq, rpb1, rpb2, attnL);
  na2d_kernel<<<dim3(16, 8, 2), dim3(512), 0, stream>>>(attnL, XT, midT);
  conv_mfma_kernel<1><<<dim3(64, 2, 4), dim3(256), 0, stream>>>(wdyb, midT, out, nullptr, bn_g, bn_b);
}